// Round 2
// baseline (6147.662 us; speedup 1.0000x reference)
//
#include <hip/hip_runtime.h>
#include <math.h>

// Workspace layout (floats):
//   [0..15]    sigma per SN weight (12 used)
//   [16..271]  dacc[4][64]  (per-layer, per-batch summed min-dist; memset 0)
//   [1296..]   hist[1024] (int, memset 0)
//   [4096..]   activation buffers, total ~118 MB
#define DEV __global__ __launch_bounds__(256)

// ---------------------------------------------------------------- spectral norm
struct SnArgs { const float* w[12]; int O[12]; int M[12]; };

DEV void sn_kernel(SnArgs a, float* __restrict__ sig) {
    int id = blockIdx.x;
    const float* W = a.w[id];
    int O = a.O[id], M = a.M[id];
    __shared__ double v[2304];
    __shared__ double red[256];
    int t = threadIdx.x;
    double u0 = 1.0 / sqrt((double)O);
    // v = W^T u  (unnormalized)
    for (int m = t; m < M; m += 256) {
        double s = 0.0;
        for (int o = 0; o < O; ++o) s += (double)W[(size_t)o * M + m];
        v[m] = s * u0;
    }
    __syncthreads();
    // ||v||
    double ps = 0.0;
    for (int m = t; m < M; m += 256) ps += v[m] * v[m];
    red[t] = ps; __syncthreads();
    for (int st = 128; st > 0; st >>= 1) { if (t < st) red[t] += red[t + st]; __syncthreads(); }
    double s1 = 1.0 / (sqrt(red[0]) + 1e-8);
    __syncthreads();
    // u2 = W v_hat ; sigma = ||u2||^2 / (||u2|| + eps)
    double ps2 = 0.0;
    for (int o = t; o < O; o += 256) {
        double s = 0.0;
        const float* Wr = W + (size_t)o * M;
        for (int m = 0; m < M; ++m) s += (double)Wr[m] * v[m];
        s *= s1;
        ps2 += s * s;
    }
    red[t] = ps2; __syncthreads();
    for (int st = 128; st > 0; st >>= 1) { if (t < st) red[t] += red[t + st]; __syncthreads(); }
    if (t == 0) {
        double n2sq = red[0];
        double n2 = sqrt(n2sq);
        sig[id] = (float)(n2sq / (n2 + 1e-8));
    }
}

// ---------------------------------------------------------------- direct conv 3x3, pad 1
// Block: 256 threads -> 8x8 spatial tile x 64 output channels.
// Thread: 2x2 output quad x 4 ocs (stride 16). OC fixed at 256.
template<int ICC, bool RELU_IN, bool POOL>
DEV void conv3x3_kernel(const float* __restrict__ in, const float* __restrict__ w,
                        const float* __restrict__ bias, const float* __restrict__ sig,
                        const float* __restrict__ res, float* __restrict__ out,
                        int C, int H) {
    __shared__ float sIn[ICC][10][10];
    __shared__ float sW[ICC * 64 * 9];
    const int OC = 256;
    int t = threadIdx.x;
    int n = blockIdx.z;
    int ocb = blockIdx.y * 64;
    int tpr = H >> 3;
    int th0 = (blockIdx.x / tpr) * 8;
    int tw0 = (blockIdx.x % tpr) * 8;
    int ocg = t & 15;
    int pix = t >> 4;                 // 16 quads
    int qr = pix >> 2, qc = pix & 3;
    int py = qr * 2, px = qc * 2;
    float scale = 1.0f / sig[0];
    float acc[4][4] = {};             // [oc_j][quad pixel: (0,0),(0,1),(1,0),(1,1)]

    for (int c0 = 0; c0 < C; c0 += ICC) {
        __syncthreads();
        // stage input tile 10x10 (halo, zero-padded)
        for (int i = t; i < ICC * 100; i += 256) {
            int ic = i / 100; int r = i - ic * 100;
            int yy = r / 10, xx = r - (r / 10) * 10;
            int gy = th0 - 1 + yy, gx = tw0 - 1 + xx;
            int gic = c0 + ic;
            float v = 0.f;
            if (gic < C && gy >= 0 && gy < H && gx >= 0 && gx < H) {
                v = in[(((size_t)n * C + gic) * H + gy) * H + gx];
                if (RELU_IN) v = fmaxf(v, 0.f);
            }
            sIn[ic][yy][xx] = v;
        }
        // stage weights [ic][oc][tap], pre-scaled by 1/sigma
        for (int i = t; i < ICC * 64 * 9; i += 256) {
            int ic = i / 576; int r = i - ic * 576;
            int oc = r / 9;  int tap = r - oc * 9;
            int gic = c0 + ic;
            float v = 0.f;
            if (gic < C) v = w[(((size_t)(ocb + oc)) * C + gic) * 9 + tap] * scale;
            sW[i] = v;
        }
        __syncthreads();
        for (int ic = 0; ic < ICC; ++ic) {
            float xi[4][4];
            #pragma unroll
            for (int yy = 0; yy < 4; ++yy)
                #pragma unroll
                for (int xx = 0; xx < 4; ++xx)
                    xi[yy][xx] = sIn[ic][py + yy][px + xx];
            #pragma unroll
            for (int j = 0; j < 4; ++j) {
                const float* wp = &sW[(ic * 64 + ocg + 16 * j) * 9];
                #pragma unroll
                for (int dy = 0; dy < 3; ++dy)
                    #pragma unroll
                    for (int dx = 0; dx < 3; ++dx) {
                        float wv = wp[dy * 3 + dx];
                        acc[j][0] += wv * xi[dy][dx];
                        acc[j][1] += wv * xi[dy][dx + 1];
                        acc[j][2] += wv * xi[dy + 1][dx];
                        acc[j][3] += wv * xi[dy + 1][dx + 1];
                    }
            }
        }
    }
    if (POOL) {
        int Ho = H >> 1;
        int oh = (th0 >> 1) + qr, ow = (tw0 >> 1) + qc;
        #pragma unroll
        for (int j = 0; j < 4; ++j) {
            int oc = ocb + ocg + 16 * j;
            float v = 0.25f * (acc[j][0] + acc[j][1] + acc[j][2] + acc[j][3]) + bias[oc];
            size_t oi = (((size_t)n * OC + oc) * Ho + oh) * Ho + ow;
            if (res) v += res[oi];
            out[oi] = v;
        }
    } else {
        #pragma unroll
        for (int j = 0; j < 4; ++j) {
            int oc = ocb + ocg + 16 * j;
            float bv = bias[oc];
            #pragma unroll
            for (int a = 0; a < 2; ++a)
                #pragma unroll
                for (int b2 = 0; b2 < 2; ++b2) {
                    int oh = th0 + py + a, ow = tw0 + px + b2;
                    float v = acc[j][a * 2 + b2] + bv;
                    size_t oi = (((size_t)n * OC + oc) * H + oh) * H + ow;
                    if (res) v += res[oi];
                    out[oi] = v;
                }
        }
    }
}

// ---------------------------------------------------------------- block-0 shortcut: h1 += conv1x1(pool2(x)) + b
DEV void sc0_kernel(const float* __restrict__ x, const float* __restrict__ wsc,
                    const float* __restrict__ bsc, const float* __restrict__ sig,
                    float* __restrict__ h1) {
    int idx = blockIdx.x * 256 + threadIdx.x;   // [n][oc][16][16] flat
    int ow = idx & 15, oh = (idx >> 4) & 15, oc = (idx >> 8) & 255, n = idx >> 16;
    float scale = 1.f / sig[0];
    float acc = bsc[oc];
    #pragma unroll
    for (int ic = 0; ic < 3; ++ic) {
        const float* xb = x + (((size_t)(n * 3 + ic)) * 32 + oh * 2) * 32 + ow * 2;
        float pv = 0.25f * (xb[0] + xb[1] + xb[32] + xb[33]);
        acc += pv * (wsc[oc * 3 + ic] * scale);
    }
    h1[idx] += acc;
}

// ---------------------------------------------------------------- block-1 shortcut: h2 += pool2(conv1x1(h1)) + b
// pool and 1x1 conv commute: compute conv1x1(pool2(h1)).
DEV void sc1_kernel(const float* __restrict__ h1, const float* __restrict__ wsc,
                    const float* __restrict__ bsc, const float* __restrict__ sig,
                    float* __restrict__ h2) {
    __shared__ float sP[64][64];    // [ic][pix]
    __shared__ float sWs[64][65];   // [oc][ic], padded
    int t = threadIdx.x;
    int n = blockIdx.x, ocb = blockIdx.y * 64;
    int ocg = t & 15, pgr = t >> 4;              // 4 consecutive pixels per thread
    float scale = 1.f / sig[0];
    float acc[4][4] = {};
    for (int c0 = 0; c0 < 256; c0 += 64) {
        __syncthreads();
        for (int i = t; i < 4096; i += 256) {
            int ic = i >> 6, p = i & 63;
            int oh = p >> 3, ow = p & 7;
            const float* hb = h1 + (((size_t)(n * 256 + c0 + ic)) * 16 + oh * 2) * 16 + ow * 2;
            sP[ic][p] = 0.25f * (hb[0] + hb[1] + hb[16] + hb[17]);
            int oc = i >> 6, ic2 = i & 63;
            sWs[oc][ic2] = wsc[(size_t)(ocb + oc) * 256 + c0 + ic2] * scale;
        }
        __syncthreads();
        for (int ic = 0; ic < 64; ++ic) {
            float pv[4];
            #pragma unroll
            for (int q = 0; q < 4; ++q) pv[q] = sP[ic][pgr * 4 + q];
            #pragma unroll
            for (int j = 0; j < 4; ++j) {
                float wv = sWs[ocg + 16 * j][ic];
                #pragma unroll
                for (int q = 0; q < 4; ++q) acc[j][q] += wv * pv[q];
            }
        }
    }
    #pragma unroll
    for (int j = 0; j < 4; ++j) {
        int oc = ocb + ocg + 16 * j;
        float bv = bsc[oc];
        #pragma unroll
        for (int q = 0; q < 4; ++q) {
            size_t oi = ((size_t)(n * 256 + oc)) * 64 + pgr * 4 + q;
            h2[oi] += acc[j][q] + bv;
        }
    }
}

// ---------------------------------------------------------------- VQ: per-pixel DIRECT min squared distance (+hist on last layer)
// D_k = sum_c (x_c - e_{c,k})^2 computed directly (matches reference's (q-xp)^2;
// non-negative terms, no cancellation). Same values drive argmin and the loss.
DEV void vq_kernel(const float* __restrict__ h, const float* __restrict__ cb,
                   float* __restrict__ dacc, int* __restrict__ hist, int HW) {
    __shared__ float sX[256][32];
    __shared__ float sE[64][64];
    __shared__ float sRV[32][16];
    __shared__ int   sRK[32][16];
    __shared__ double sSum[32];
    int t = threadIdx.x;
    int pix0 = blockIdx.x * 32;
    int n = pix0 / HW, s0 = pix0 % HW;
    const float* hb = h + (size_t)n * 256 * HW + s0;
    for (int i = t; i < 256 * 32; i += 256) { int c = i >> 5, p = i & 31; sX[c][p] = hb[(size_t)c * HW + p]; }
    __syncthreads();
    int pg = t >> 4, kg = t & 15;
    int p0 = pg * 2, p1 = p0 + 1;
    float bestv0 = 3.0e38f, bestv1 = 3.0e38f; int bestk0 = 0, bestk1 = 0;
    for (int k0 = 0; k0 < 1024; k0 += 64) {
        float acc0[4] = {}, acc1[4] = {};
        for (int c0 = 0; c0 < 256; c0 += 64) {
            __syncthreads();
            for (int i = t; i < 4096; i += 256) { int c = i >> 6, k = i & 63; sE[c][k] = cb[(size_t)(c0 + c) * 1024 + k0 + k]; }
            __syncthreads();
            #pragma unroll 4
            for (int c = 0; c < 64; ++c) {
                float x0 = sX[c0 + c][p0], x1 = sX[c0 + c][p1];
                #pragma unroll
                for (int jj = 0; jj < 4; ++jj) {
                    float e = sE[c][kg * 4 + jj];
                    float d0 = x0 - e, d1 = x1 - e;
                    acc0[jj] += d0 * d0;
                    acc1[jj] += d1 * d1;
                }
            }
        }
        #pragma unroll
        for (int jj = 0; jj < 4; ++jj) {
            int k = k0 + kg * 4 + jj;
            if (acc0[jj] < bestv0) { bestv0 = acc0[jj]; bestk0 = k; }
            if (acc1[jj] < bestv1) { bestv1 = acc1[jj]; bestk1 = k; }
        }
    }
    sRV[p0][kg] = bestv0; sRK[p0][kg] = bestk0;
    sRV[p1][kg] = bestv1; sRK[p1][kg] = bestk1;
    __syncthreads();
    if (t < 32) {
        float bv = 3.0e38f; int bk = 0;
        for (int kk = 0; kk < 16; ++kk) {
            float v = sRV[t][kk]; int k = sRK[t][kk];
            if (v < bv || (v == bv && k < bk)) { bv = v; bk = k; }
        }
        sSum[t] = (double)bv;
        if (hist) atomicAdd(hist + bk, 1);
    }
    __syncthreads();
    if (t == 0) {
        double s = 0.0;
        for (int i = 0; i < 32; ++i) s += sSum[i];
        atomicAdd(dacc + n, (float)s);
    }
}

// ---------------------------------------------------------------- head: hf, out, quant_loss
DEV void head_kernel(const float* __restrict__ h4, const float* __restrict__ lin_w,
                     const float* __restrict__ lin_b, const float* __restrict__ emb_w,
                     const int* __restrict__ y, const float* __restrict__ sig,
                     const float* __restrict__ dacc, float* __restrict__ out) {
    __shared__ double r1[256], r2[256];
    int b = blockIdx.x, t = threadIdx.x;
    const float* hb = h4 + ((size_t)b * 256 + t) * 64;
    float s = 0.f;
    #pragma unroll 4
    for (int i = 0; i < 64; ++i) s += fmaxf(hb[i], 0.f);
    int yb = y[b];
    r1[t] = (double)s * (double)lin_w[t];
    r2[t] = (double)s * (double)emb_w[(size_t)yb * 256 + t];
    __syncthreads();
    for (int st = 128; st > 0; st >>= 1) { if (t < st) { r1[t] += r1[t + st]; r2[t] += r2[t + st]; } __syncthreads(); }
    if (t == 0) {
        out[b] = (float)(r1[0] / (double)sig[10] + (double)lin_b[0] + r2[0] / (double)sig[11]);
        out[64 + b] = (float)(0.5 * ((double)dacc[b] * (1.0 / 65536.0)
                              + ((double)dacc[64 + b] + (double)dacc[128 + b] + (double)dacc[192 + b]) * (1.0 / 16384.0)));
    }
}

DEV void ppl_kernel(const int* __restrict__ hist, float* __restrict__ outp) {
    __shared__ double red[256];
    int t = threadIdx.x;
    double s = 0.0;
    for (int k = t; k < 1024; k += 256) {
        double p = (double)hist[k] * (1.0 / 4096.0);
        s += p * log(p + 1e-10);
    }
    red[t] = s; __syncthreads();
    for (int st = 128; st > 0; st >>= 1) { if (t < st) red[t] += red[t + st]; __syncthreads(); }
    if (t == 0) outp[0] = (float)exp(-red[0]);
}

// ---------------------------------------------------------------- launch
extern "C" void kernel_launch(void* const* d_in, const int* in_sizes, int n_in,
                              void* d_out, int out_size, void* d_ws, size_t ws_size,
                              hipStream_t stream) {
    (void)in_sizes; (void)n_in; (void)out_size; (void)ws_size;
    const float* x      = (const float*)d_in[0];
    const int*   y      = (const int*)  d_in[1];
    const float* b0_w1  = (const float*)d_in[2];
    const float* b0_b1  = (const float*)d_in[3];
    const float* b0_w2  = (const float*)d_in[4];
    const float* b0_b2  = (const float*)d_in[5];
    const float* b0_wsc = (const float*)d_in[6];
    const float* b0_bsc = (const float*)d_in[7];
    const float* b1_w1  = (const float*)d_in[8];
    const float* b1_b1  = (const float*)d_in[9];
    const float* b1_w2  = (const float*)d_in[10];
    const float* b1_b2  = (const float*)d_in[11];
    const float* b1_wsc = (const float*)d_in[12];
    const float* b1_bsc = (const float*)d_in[13];
    const float* b2_w1  = (const float*)d_in[14];
    const float* b2_b1  = (const float*)d_in[15];
    const float* b2_w2  = (const float*)d_in[16];
    const float* b2_b2  = (const float*)d_in[17];
    const float* b3_w1  = (const float*)d_in[18];
    const float* b3_b1  = (const float*)d_in[19];
    const float* b3_w2  = (const float*)d_in[20];
    const float* b3_b2  = (const float*)d_in[21];
    const float* cb0    = (const float*)d_in[22];
    const float* cb1    = (const float*)d_in[23];
    const float* cb2    = (const float*)d_in[24];
    const float* cb3    = (const float*)d_in[25];
    const float* lin_w  = (const float*)d_in[26];
    const float* lin_b  = (const float*)d_in[27];
    const float* emb_w  = (const float*)d_in[28];
    float* out = (float*)d_out;

    float* wsf  = (float*)d_ws;
    float* sig  = wsf;
    float* dacc = wsf + 16;
    int*   hist = (int*)(wsf + 1296);
    float* A    = wsf + 4096;            // [64,256,32,32]
    float* h1   = A  + 16777216;         // [64,256,16,16]
    float* tb   = h1 + 4194304;          // [64,256,16,16]
    float* h2   = tb + 4194304;          // [64,256,8,8]
    float* t2   = h2 + 1048576;          // [64,256,8,8]
    float* h3   = t2 + 1048576;          // [64,256,8,8]
    float* h4   = h3 + 1048576;          // [64,256,8,8]

    hipMemsetAsync(dacc, 0, 256 * sizeof(float), stream);
    hipMemsetAsync(hist, 0, 1024 * sizeof(int), stream);

    SnArgs sa;
    const float* sw[12] = {b0_w1, b0_w2, b0_wsc, b1_w1, b1_w2, b1_wsc,
                           b2_w1, b2_w2, b3_w1, b3_w2, lin_w, emb_w};
    int sO[12] = {256, 256, 256, 256, 256, 256, 256, 256, 256, 256, 1, 100};
    int sM[12] = {27, 2304, 3, 2304, 2304, 256, 2304, 2304, 2304, 2304, 256, 256};
    for (int i = 0; i < 12; ++i) { sa.w[i] = sw[i]; sa.O[i] = sO[i]; sa.M[i] = sM[i]; }
    sn_kernel<<<12, 256, 0, stream>>>(sa, sig);

    // block 0 (preact=false, down): conv -> relu-conv -> pool ; sc = conv1x1(pool(x))
    conv3x3_kernel<4, false, false><<<dim3(16, 4, 64), 256, 0, stream>>>(x, b0_w1, b0_b1, sig + 0, nullptr, A, 3, 32);
    conv3x3_kernel<16, true, true><<<dim3(16, 4, 64), 256, 0, stream>>>(A, b0_w2, b0_b2, sig + 1, nullptr, h1, 256, 32);
    sc0_kernel<<<16384, 256, 0, stream>>>(x, b0_wsc, b0_bsc, sig + 2, h1);
    vq_kernel<<<512, 256, 0, stream>>>(h1, cb0, dacc + 0, nullptr, 256);

    // block 1 (preact=true, down)
    conv3x3_kernel<16, true, false><<<dim3(4, 4, 64), 256, 0, stream>>>(h1, b1_w1, b1_b1, sig + 3, nullptr, tb, 256, 16);
    conv3x3_kernel<16, true, true><<<dim3(4, 4, 64), 256, 0, stream>>>(tb, b1_w2, b1_b2, sig + 4, nullptr, h2, 256, 16);
    sc1_kernel<<<dim3(64, 4), 256, 0, stream>>>(h1, b1_wsc, b1_bsc, sig + 5, h2);
    vq_kernel<<<128, 256, 0, stream>>>(h2, cb1, dacc + 64, nullptr, 64);

    // block 2 (preact=true, identity sc)
    conv3x3_kernel<16, true, false><<<dim3(1, 4, 64), 256, 0, stream>>>(h2, b2_w1, b2_b1, sig + 6, nullptr, t2, 256, 8);
    conv3x3_kernel<16, true, false><<<dim3(1, 4, 64), 256, 0, stream>>>(t2, b2_w2, b2_b2, sig + 7, h2, h3, 256, 8);
    vq_kernel<<<128, 256, 0, stream>>>(h3, cb2, dacc + 128, nullptr, 64);

    // block 3
    conv3x3_kernel<16, true, false><<<dim3(1, 4, 64), 256, 0, stream>>>(h3, b3_w1, b3_b1, sig + 8, nullptr, t2, 256, 8);
    conv3x3_kernel<16, true, false><<<dim3(1, 4, 64), 256, 0, stream>>>(t2, b3_w2, b3_b2, sig + 9, h3, h4, 256, 8);
    vq_kernel<<<128, 256, 0, stream>>>(h4, cb3, dacc + 192, hist, 64);

    head_kernel<<<64, 256, 0, stream>>>(h4, lin_w, lin_b, emb_w, y, sig, dacc, out);
    ppl_kernel<<<1, 256, 0, stream>>>(hist, out + 128);
}

// Round 5
// 2447.979 us; speedup vs baseline: 2.5113x; 2.5113x over previous
//
#include <hip/hip_runtime.h>
#include <math.h>

#define DEV __global__ __launch_bounds__(256)

typedef __attribute__((ext_vector_type(8))) short s8v;   // 8 bf16
typedef __attribute__((ext_vector_type(4))) float f4v;   // mfma acc

__device__ inline ushort f2bf(float x) {
    unsigned u = __float_as_uint(x);
    unsigned r = (u + 0x7FFFu + ((u >> 16) & 1u)) >> 16;   // RNE
    return (ushort)r;
}
__device__ inline float bf2f(ushort h) { return __uint_as_float(((unsigned)h) << 16); }

// ---------------------------------------------------------------- spectral norm (fp64, exact)
struct SnArgs { const float* w[12]; int O[12]; int M[12]; };

DEV void sn_kernel(SnArgs a, float* __restrict__ sig) {
    int id = blockIdx.x;
    const float* W = a.w[id];
    int O = a.O[id], M = a.M[id];
    __shared__ double v[2304];
    __shared__ double red[256];
    int t = threadIdx.x;
    double u0 = 1.0 / sqrt((double)O);
    for (int m = t; m < M; m += 256) {
        double s = 0.0;
        for (int o = 0; o < O; ++o) s += (double)W[(size_t)o * M + m];
        v[m] = s * u0;
    }
    __syncthreads();
    double ps = 0.0;
    for (int m = t; m < M; m += 256) ps += v[m] * v[m];
    red[t] = ps; __syncthreads();
    for (int st = 128; st > 0; st >>= 1) { if (t < st) red[t] += red[t + st]; __syncthreads(); }
    double s1 = 1.0 / (sqrt(red[0]) + 1e-8);
    __syncthreads();
    double ps2 = 0.0;
    for (int o = t; o < O; o += 256) {
        double s = 0.0;
        const float* Wr = W + (size_t)o * M;
        for (int m = 0; m < M; ++m) s += (double)Wr[m] * v[m];
        s *= s1;
        ps2 += s * s;
    }
    red[t] = ps2; __syncthreads();
    for (int st = 128; st > 0; st >>= 1) { if (t < st) red[t] += red[t + st]; __syncthreads(); }
    if (t == 0) {
        double n2sq = red[0];
        sig[id] = (float)(n2sq / (sqrt(n2sq) + 1e-8));
    }
}

// ---------------------------------------------------------------- weight prep: w/sigma -> split bf16 [tap][icc][oc][32ic], hi+lo planes
struct PrepArgs { const float* w[8]; int C[8]; int sigidx[8]; int outoff[8]; int nel[8]; };

DEV void prep_kernel(PrepArgs a, const float* __restrict__ sig, ushort* __restrict__ wp) {
    int gid = blockIdx.x * 256 + threadIdx.x;
    int L = 0, cum = 0;
    for (int i = 0; i < 8; ++i) { if (gid >= cum && gid < cum + a.nel[i]) { L = i; break; } cum += a.nel[i]; }
    if (gid >= cum + a.nel[L]) return;
    int e = gid - cum;
    int C = a.C[L];
    int NICC = (C + 31) >> 5;
    int icl = e & 31;
    int oc = (e >> 5) & 255;
    int icc = (e >> 13) % NICC;
    int tap = e / (8192 * NICC);
    int ic = icc * 32 + icl;
    float v = 0.f;
    if (ic < C) v = a.w[L][((size_t)oc * C + ic) * 9 + tap] / sig[a.sigidx[L]];
    ushort h = f2bf(v);
    ushort l = f2bf(v - bf2f(h));
    wp[a.outoff[L] + e] = h;
    wp[a.outoff[L] + a.nel[L] + e] = l;
}

// ---------------------------------------------------------------- MFMA implicit-GEMM 3x3 conv, pad 1
// M-tile = ST*64 pixels (ST spatial 8x8 tiles), N-tile = NTW*64 oc (4 waves n-split),
// K = 9 taps x NICC*32 ic. A staged in LDS [pos][ic] (stride 40, split hi/lo bf16);
// B fragments loaded directly from prepped global weights (coalesced, L2).
template<int ST, int NTW, int NICC, bool RELU, bool POOL, bool RES, bool INS, bool OUTS>
DEV void conv_mfma(const float* __restrict__ in, const ushort* __restrict__ inhi,
                   const ushort* __restrict__ inlo, const ushort* __restrict__ wp,
                   const float* __restrict__ bias, const float* __restrict__ res,
                   float* __restrict__ out, ushort* __restrict__ outhi, ushort* __restrict__ outlo,
                   int C, int H) {
    const int MT = ST * 4;
    const int PLANE = NICC * 73728;           // 9*NICC*256*32
    __shared__ ushort sH[ST * 100 * 40];
    __shared__ ushort sL[ST * 100 * 40];
    int t = threadIdx.x;
    int wid = t >> 6, lane = t & 63, quad = lane >> 4, l15 = lane & 15;
    int n = blockIdx.z;
    int ocb = blockIdx.y * (NTW * 64) + wid * (NTW * 16);
    int tpr = H >> 3;
    int tIdx0 = blockIdx.x * ST;

    int abase[MT];
    #pragma unroll
    for (int mt = 0; mt < MT; ++mt) {
        int m64 = (mt & 3) * 16 + l15;
        abase[mt] = (((mt >> 2) * 100 + (m64 >> 3) * 10 + (m64 & 7)) * 40) + quad * 8;
    }

    f4v acc[MT][NTW];
    #pragma unroll
    for (int mt = 0; mt < MT; ++mt)
        #pragma unroll
        for (int nt = 0; nt < NTW; ++nt)
            acc[mt][nt] = (f4v){0.f, 0.f, 0.f, 0.f};

    for (int icc = 0; icc < NICC; ++icc) {
        __syncthreads();
        const int NSTAGE = ST * 100 * 32;
        for (int i = t; i < NSTAGE; i += 256) {
            int ic = i / (ST * 100);
            int rr = i - ic * (ST * 100);
            int tile = rr / 100, pos = rr - (rr / 100) * 100;
            int tIdx = tIdx0 + tile;
            int th0 = (tIdx / tpr) * 8, tw0 = (tIdx % tpr) * 8;
            int gy = th0 - 1 + pos / 10, gx = tw0 - 1 + (pos % 10);
            int gic = icc * 32 + ic;
            ushort hv = 0, lv = 0;
            if (gic < C && gy >= 0 && gy < H && gx >= 0 && gx < H) {
                size_t gi = (((size_t)n * C + gic) * H + gy) * H + gx;
                if (INS) { hv = inhi[gi]; lv = inlo[gi]; }
                else {
                    float v = in[gi];
                    if (RELU) v = fmaxf(v, 0.f);
                    hv = f2bf(v);
                    lv = f2bf(v - bf2f(hv));
                }
            }
            int si = (tile * 100 + pos) * 40 + ic;
            sH[si] = hv; sL[si] = lv;
        }
        __syncthreads();
        for (int tap = 0; tap < 9; ++tap) {
            int toff = ((tap / 3) * 10 + (tap % 3)) * 40;
            s8v bh[NTW], bl[NTW];
            size_t wbase = (size_t)(tap * NICC + icc) * 8192;
            #pragma unroll
            for (int nt = 0; nt < NTW; ++nt) {
                size_t wo = wbase + (size_t)(ocb + nt * 16 + l15) * 32 + quad * 8;
                bh[nt] = *(const s8v*)(wp + wo);
                bl[nt] = *(const s8v*)(wp + PLANE + wo);
            }
            #pragma unroll
            for (int mt = 0; mt < MT; ++mt) {
                s8v ah = *(const s8v*)(&sH[abase[mt] + toff]);
                s8v al = *(const s8v*)(&sL[abase[mt] + toff]);
                #pragma unroll
                for (int nt = 0; nt < NTW; ++nt) {
                    acc[mt][nt] = __builtin_amdgcn_mfma_f32_16x16x32_bf16(al, bh[nt], acc[mt][nt], 0, 0, 0);
                    acc[mt][nt] = __builtin_amdgcn_mfma_f32_16x16x32_bf16(ah, bl[nt], acc[mt][nt], 0, 0, 0);
                    acc[mt][nt] = __builtin_amdgcn_mfma_f32_16x16x32_bf16(ah, bh[nt], acc[mt][nt], 0, 0, 0);
                }
            }
        }
    }

    // epilogue: D[m = (mt&3)*16 + quad*4 + r][oc = ocb + nt*16 + l15]
    #pragma unroll
    for (int nt = 0; nt < NTW; ++nt) {
        int oc = ocb + nt * 16 + l15;
        float bv = bias[oc];
        #pragma unroll
        for (int mt = 0; mt < MT; ++mt) {
            int tIdx = tIdx0 + (mt >> 2);
            int th0 = (tIdx / tpr) * 8, tw0 = (tIdx % tpr) * 8;
            if (POOL) {
                float s01 = acc[mt][nt][0] + acc[mt][nt][1];
                float s23 = acc[mt][nt][2] + acc[mt][nt][3];
                float o01 = s01 + __shfl_down(s01, 32, 64);
                float o23 = s23 + __shfl_down(s23, 32, 64);
                if (quad < 2) {
                    int Ho = H >> 1;
                    int oy = (th0 >> 1) + (mt & 3);
                    int ox = (tw0 >> 1) + quad * 2;
                    size_t ob = ((size_t)(n * 256 + oc) * Ho + oy) * Ho;
                    out[ob + ox] = 0.25f * o01 + bv;
                    out[ob + ox + 1] = 0.25f * o23 + bv;
                }
            } else {
                #pragma unroll
                for (int r = 0; r < 4; ++r) {
                    int p16 = quad * 4 + r;
                    int y = th0 + (mt & 3) * 2 + (p16 >> 3);
                    int x = tw0 + (p16 & 7);
                    size_t oi = (((size_t)(n * 256 + oc)) * H + y) * H + x;
                    float v = acc[mt][nt][r] + bv;
                    if (RES) v += res[oi];
                    if (OUTS) {
                        v = fmaxf(v, 0.f);
                        ushort h = f2bf(v);
                        outhi[oi] = h;
                        outlo[oi] = f2bf(v - bf2f(h));
                    } else {
                        out[oi] = v;
                    }
                }
            }
        }
    }
}

// ---------------------------------------------------------------- block-0 shortcut: h1 += conv1x1(pool2(x)) + b
DEV void sc0_kernel(const float* __restrict__ x, const float* __restrict__ wsc,
                    const float* __restrict__ bsc, const float* __restrict__ sig,
                    float* __restrict__ h1) {
    int idx = blockIdx.x * 256 + threadIdx.x;
    int ow = idx & 15, oh = (idx >> 4) & 15, oc = (idx >> 8) & 255, n = idx >> 16;
    float scale = 1.f / sig[0];
    float acc = bsc[oc];
    #pragma unroll
    for (int ic = 0; ic < 3; ++ic) {
        const float* xb = x + (((size_t)(n * 3 + ic)) * 32 + oh * 2) * 32 + ow * 2;
        float pv = 0.25f * (xb[0] + xb[1] + xb[32] + xb[33]);
        acc += pv * (wsc[oc * 3 + ic] * scale);
    }
    h1[idx] += acc;
}

// ---------------------------------------------------------------- block-1 shortcut: h2 += conv1x1(pool2(h1)) + b
DEV void sc1_kernel(const float* __restrict__ h1, const float* __restrict__ wsc,
                    const float* __restrict__ bsc, const float* __restrict__ sig,
                    float* __restrict__ h2) {
    __shared__ float sP[64][64];
    __shared__ float sWs[64][65];
    int t = threadIdx.x;
    int n = blockIdx.x, ocb = blockIdx.y * 64;
    int ocg = t & 15, pgr = t >> 4;
    float scale = 1.f / sig[0];
    float acc[4][4] = {};
    for (int c0 = 0; c0 < 256; c0 += 64) {
        __syncthreads();
        for (int i = t; i < 4096; i += 256) {
            int ic = i >> 6, p = i & 63;
            int oh = p >> 3, ow = p & 7;
            const float* hb = h1 + (((size_t)(n * 256 + c0 + ic)) * 16 + oh * 2) * 16 + ow * 2;
            sP[ic][p] = 0.25f * (hb[0] + hb[1] + hb[16] + hb[17]);
            int oc = i >> 6, ic2 = i & 63;
            sWs[oc][ic2] = wsc[(size_t)(ocb + oc) * 256 + c0 + ic2] * scale;
        }
        __syncthreads();
        for (int ic = 0; ic < 64; ++ic) {
            float pv[4];
            #pragma unroll
            for (int q = 0; q < 4; ++q) pv[q] = sP[ic][pgr * 4 + q];
            #pragma unroll
            for (int j = 0; j < 4; ++j) {
                float wv = sWs[ocg + 16 * j][ic];
                #pragma unroll
                for (int q = 0; q < 4; ++q) acc[j][q] += wv * pv[q];
            }
        }
    }
    #pragma unroll
    for (int j = 0; j < 4; ++j) {
        int oc = ocb + ocg + 16 * j;
        float bv = bsc[oc];
        #pragma unroll
        for (int q = 0; q < 4; ++q) {
            size_t oi = ((size_t)(n * 256 + oc)) * 64 + pgr * 4 + q;
            h2[oi] += acc[j][q] + bv;
        }
    }
}

// ---------------------------------------------------------------- VQ: direct min squared distance, block = 32 pixels x 256 codes
// Packed (distbits<<32 | k) u64 atomicMin gives global argmin with first-k tie-break.
DEV void vq_kernel(const float* __restrict__ h, const float* __restrict__ cb,
                   unsigned long long* __restrict__ mb, int HW) {
    __shared__ float sX[256][32];
    __shared__ float sE[64][64];
    __shared__ float sRV[32][16];
    __shared__ int   sRK[32][16];
    int t = threadIdx.x;
    int pix0 = blockIdx.x * 32;
    int k00 = blockIdx.y * 256;
    int n = pix0 / HW, s0 = pix0 % HW;
    const float* hb = h + (size_t)n * 256 * HW + s0;
    for (int i = t; i < 8192; i += 256) { int c = i >> 5, p = i & 31; sX[c][p] = hb[(size_t)c * HW + p]; }
    int pg = t >> 4, kg = t & 15;
    int p0 = pg * 2, p1 = p0 + 1;
    float bv0 = 3.0e38f, bv1 = 3.0e38f; int bk0 = 0, bk1 = 0;
    for (int k0 = 0; k0 < 4; ++k0) {
        float a0[4] = {}, a1[4] = {};
        for (int c0 = 0; c0 < 4; ++c0) {
            __syncthreads();
            for (int i = t; i < 4096; i += 256) {
                int c = i >> 6, k = i & 63;
                sE[c][k] = cb[(size_t)(c0 * 64 + c) * 1024 + k00 + k0 * 64 + k];
            }
            __syncthreads();
            #pragma unroll 4
            for (int c = 0; c < 64; ++c) {
                float x0 = sX[c0 * 64 + c][p0], x1 = sX[c0 * 64 + c][p1];
                #pragma unroll
                for (int j = 0; j < 4; ++j) {
                    float e = sE[c][kg * 4 + j];
                    float d0 = x0 - e, d1 = x1 - e;
                    a0[j] += d0 * d0;
                    a1[j] += d1 * d1;
                }
            }
        }
        #pragma unroll
        for (int j = 0; j < 4; ++j) {
            int k = k00 + k0 * 64 + kg * 4 + j;
            if (a0[j] < bv0) { bv0 = a0[j]; bk0 = k; }
            if (a1[j] < bv1) { bv1 = a1[j]; bk1 = k; }
        }
    }
    sRV[p0][kg] = bv0; sRK[p0][kg] = bk0;
    sRV[p1][kg] = bv1; sRK[p1][kg] = bk1;
    __syncthreads();
    if (t < 32) {
        float bv = 3.0e38f; int bk = 0;
        for (int kk = 0; kk < 16; ++kk) {
            float v = sRV[t][kk]; int k = sRK[t][kk];
            if (v < bv || (v == bv && k < bk)) { bv = v; bk = k; }
        }
        unsigned long long pk = ((unsigned long long)__float_as_uint(bv) << 32) | (unsigned)bk;
        atomicMin(mb + pix0 + t, pk);
    }
}

DEV void vq_finalize(const unsigned long long* __restrict__ mb,
                     float* __restrict__ dacc, int* __restrict__ hist) {
    int gid = blockIdx.x * 256 + threadIdx.x;   // 0..28671
    unsigned long long pk = mb[gid];
    float bv = __uint_as_float((unsigned)(pk >> 32));
    int k = (int)(unsigned)(pk & 0xFFFFFFFFu);
    int layer, n;
    if (gid < 16384) { layer = 0; n = gid >> 8; }
    else { int r = gid - 16384; layer = 1 + r / 4096; n = (r & 4095) >> 6; }
    atomicAdd(dacc + layer * 64 + n, bv);
    if (gid >= 24576) atomicAdd(hist + k, 1);
}

// ---------------------------------------------------------------- head + ppl
DEV void head_kernel(const float* __restrict__ h4, const float* __restrict__ lin_w,
                     const float* __restrict__ lin_b, const float* __restrict__ emb_w,
                     const int* __restrict__ y, const float* __restrict__ sig,
                     const float* __restrict__ dacc, float* __restrict__ out) {
    __shared__ double r1[256], r2[256];
    int b = blockIdx.x, t = threadIdx.x;
    const float* hb = h4 + ((size_t)b * 256 + t) * 64;
    float s = 0.f;
    #pragma unroll 4
    for (int i = 0; i < 64; ++i) s += fmaxf(hb[i], 0.f);
    int yb = y[b];
    r1[t] = (double)s * (double)lin_w[t];
    r2[t] = (double)s * (double)emb_w[(size_t)yb * 256 + t];
    __syncthreads();
    for (int st = 128; st > 0; st >>= 1) { if (t < st) { r1[t] += r1[t + st]; r2[t] += r2[t + st]; } __syncthreads(); }
    if (t == 0) {
        out[b] = (float)(r1[0] / (double)sig[10] + (double)lin_b[0] + r2[0] / (double)sig[11]);
        out[64 + b] = (float)(0.5 * ((double)dacc[b] * (1.0 / 65536.0)
                              + ((double)dacc[64 + b] + (double)dacc[128 + b] + (double)dacc[192 + b]) * (1.0 / 16384.0)));
    }
}

DEV void ppl_kernel(const int* __restrict__ hist, float* __restrict__ outp) {
    __shared__ double red[256];
    int t = threadIdx.x;
    double s = 0.0;
    for (int k = t; k < 1024; k += 256) {
        double p = (double)hist[k] * (1.0 / 4096.0);
        s += p * log(p + 1e-10);
    }
    red[t] = s; __syncthreads();
    for (int st = 128; st > 0; st >>= 1) { if (t < st) red[t] += red[t + st]; __syncthreads(); }
    if (t == 0) outp[0] = (float)exp(-red[0]);
}

// ---------------------------------------------------------------- launch
extern "C" void kernel_launch(void* const* d_in, const int* in_sizes, int n_in,
                              void* d_out, int out_size, void* d_ws, size_t ws_size,
                              hipStream_t stream) {
    (void)in_sizes; (void)n_in; (void)out_size; (void)ws_size;
    const float* x      = (const float*)d_in[0];
    const int*   y      = (const int*)  d_in[1];
    const float* b0_w1  = (const float*)d_in[2];
    const float* b0_b1  = (const float*)d_in[3];
    const float* b0_w2  = (const float*)d_in[4];
    const float* b0_b2  = (const float*)d_in[5];
    const float* b0_wsc = (const float*)d_in[6];
    const float* b0_bsc = (const float*)d_in[7];
    const float* b1_w1  = (const float*)d_in[8];
    const float* b1_b1  = (const float*)d_in[9];
    const float* b1_w2  = (const float*)d_in[10];
    const float* b1_b2  = (const float*)d_in[11];
    const float* b1_wsc = (const float*)d_in[12];
    const float* b1_bsc = (const float*)d_in[13];
    const float* b2_w1  = (const float*)d_in[14];
    const float* b2_b1  = (const float*)d_in[15];
    const float* b2_w2  = (const float*)d_in[16];
    const float* b2_b2  = (const float*)d_in[17];
    const float* b3_w1  = (const float*)d_in[18];
    const float* b3_b1  = (const float*)d_in[19];
    const float* b3_w2  = (const float*)d_in[20];
    const float* b3_b2  = (const float*)d_in[21];
    const float* cb0    = (const float*)d_in[22];
    const float* cb1    = (const float*)d_in[23];
    const float* cb2    = (const float*)d_in[24];
    const float* cb3    = (const float*)d_in[25];
    const float* lin_w  = (const float*)d_in[26];
    const float* lin_b  = (const float*)d_in[27];
    const float* emb_w  = (const float*)d_in[28];
    float* out = (float*)d_out;

    // ---- workspace map (floats, NO overlaps except tb/t2 in dead-A region) ----
    float* wsf  = (float*)d_ws;
    float* sig  = wsf;                                           // [0,16)
    float* dacc = wsf + 16;                                      // [16,272)
    int*   hist = (int*)(wsf + 1296);                            // [1296,2320) ints
    unsigned long long* mb = (unsigned long long*)(wsf + 4096);  // 28672 u64 -> [4096,61440) DISJOINT from hist
    ushort* Ahi = (ushort*)(wsf + 65536);                        // 16777216 ush = [65536,8454144) f
    ushort* Alo = Ahi + 16777216;                                // [8454144,16842752) f
    float* h1 = wsf + 16842752;                                  // [16842752,21037056)
    float* h2 = h1 + 4194304;                                    // [21037056,22085632)
    float* h3 = h2 + 1048576;                                    // [22085632,23134208)
    float* h4 = h3 + 1048576;                                    // [23134208,24182784)
    float* tb = wsf + 65536;                                     // aliases dead A (after conv0_2)
    float* t2 = wsf + 65536 + 4194304;                           // aliases dead A
    ushort* wp = (ushort*)(wsf + 24182784);                      // 8404992 ush -> ends f 28385280

    hipMemsetAsync(dacc, 0, 256 * sizeof(float), stream);
    hipMemsetAsync(hist, 0, 1024 * sizeof(int), stream);
    hipMemsetAsync(mb, 0xFF, 28672 * sizeof(unsigned long long), stream);

    SnArgs sa;
    const float* sw[12] = {b0_w1, b0_w2, b0_wsc, b1_w1, b1_w2, b1_wsc,
                           b2_w1, b2_w2, b3_w1, b3_w2, lin_w, emb_w};
    int sO[12] = {256, 256, 256, 256, 256, 256, 256, 256, 256, 256, 1, 100};
    int sM[12] = {27, 2304, 3, 2304, 2304, 256, 2304, 2304, 2304, 2304, 256, 256};
    for (int i = 0; i < 12; ++i) { sa.w[i] = sw[i]; sa.O[i] = sO[i]; sa.M[i] = sM[i]; }
    sn_kernel<<<12, 256, 0, stream>>>(sa, sig);

    PrepArgs pa;
    const float* pw[8] = {b0_w1, b0_w2, b1_w1, b1_w2, b2_w1, b2_w2, b3_w1, b3_w2};
    int pC[8]   = {3, 256, 256, 256, 256, 256, 256, 256};
    int pS[8]   = {0, 1, 3, 4, 6, 7, 8, 9};
    int pOff[8] = {0, 147456, 1327104, 2506752, 3686400, 4866048, 6045696, 7225344};
    int pN[8]   = {73728, 589824, 589824, 589824, 589824, 589824, 589824, 589824};
    for (int i = 0; i < 8; ++i) { pa.w[i] = pw[i]; pa.C[i] = pC[i]; pa.sigidx[i] = pS[i]; pa.outoff[i] = pOff[i]; pa.nel[i] = pN[i]; }
    prep_kernel<<<16416, 256, 0, stream>>>(pa, sig, wp);

    // block 0: conv0_1 (x, no relu-in, split-out) -> conv0_2 (split-in, pool) ; sc0 ; vq0
    conv_mfma<2, 4, 1, false, false, false, false, true><<<dim3(8, 1, 64), 256, 0, stream>>>(
        x, nullptr, nullptr, wp + 0, b0_b1, nullptr, nullptr, Ahi, Alo, 3, 32);
    conv_mfma<2, 4, 8, true, true, false, true, false><<<dim3(8, 1, 64), 256, 0, stream>>>(
        nullptr, Ahi, Alo, wp + 147456, b0_b2, nullptr, h1, nullptr, nullptr, 256, 32);
    sc0_kernel<<<16384, 256, 0, stream>>>(x, b0_wsc, b0_bsc, sig + 2, h1);
    vq_kernel<<<dim3(512, 4), 256, 0, stream>>>(h1, cb0, mb + 0, 256);

    // block 1
    conv_mfma<2, 2, 8, true, false, false, false, false><<<dim3(2, 2, 64), 256, 0, stream>>>(
        h1, nullptr, nullptr, wp + 1327104, b1_b1, nullptr, tb, nullptr, nullptr, 256, 16);
    conv_mfma<2, 2, 8, true, true, false, false, false><<<dim3(2, 2, 64), 256, 0, stream>>>(
        tb, nullptr, nullptr, wp + 2506752, b1_b2, nullptr, h2, nullptr, nullptr, 256, 16);
    sc1_kernel<<<dim3(64, 4), 256, 0, stream>>>(h1, b1_wsc, b1_bsc, sig + 5, h2);
    vq_kernel<<<dim3(128, 4), 256, 0, stream>>>(h2, cb1, mb + 16384, 64);

    // block 2 (identity sc: residual in conv2_2 epilogue)
    conv_mfma<1, 1, 8, true, false, false, false, false><<<dim3(1, 4, 64), 256, 0, stream>>>(
        h2, nullptr, nullptr, wp + 3686400, b2_b1, nullptr, t2, nullptr, nullptr, 256, 8);
    conv_mfma<1, 1, 8, true, false, true, false, false><<<dim3(1, 4, 64), 256, 0, stream>>>(
        t2, nullptr, nullptr, wp + 4866048, b2_b2, h2, h3, nullptr, nullptr, 256, 8);
    vq_kernel<<<dim3(128, 4), 256, 0, stream>>>(h3, cb2, mb + 20480, 64);

    // block 3
    conv_mfma<1, 1, 8, true, false, false, false, false><<<dim3(1, 4, 64), 256, 0, stream>>>(
        h3, nullptr, nullptr, wp + 6045696, b3_b1, nullptr, t2, nullptr, nullptr, 256, 8);
    conv_mfma<1, 1, 8, true, false, true, false, false><<<dim3(1, 4, 64), 256, 0, stream>>>(
        t2, nullptr, nullptr, wp + 7225344, b3_b2, h3, h4, nullptr, nullptr, 256, 8);
    vq_kernel<<<dim3(128, 4), 256, 0, stream>>>(h4, cb3, mb + 24576, 64);

    vq_finalize<<<112, 256, 0, stream>>>(mb, dacc, hist);
    head_kernel<<<64, 256, 0, stream>>>(h4, lin_w, lin_b, emb_w, y, sig, dacc, out);
    ppl_kernel<<<1, 256, 0, stream>>>(hist, out + 128);
}

// Round 6
// 1928.489 us; speedup vs baseline: 3.1878x; 1.2694x over previous
//
#include <hip/hip_runtime.h>
#include <math.h>

#define DEV __global__ __launch_bounds__(256)

typedef __attribute__((ext_vector_type(8))) short s8v;   // 8 bf16
typedef __attribute__((ext_vector_type(4))) float f4v;   // mfma acc

__device__ inline ushort f2bf(float x) {
    unsigned u = __float_as_uint(x);
    unsigned r = (u + 0x7FFFu + ((u >> 16) & 1u)) >> 16;   // RNE
    return (ushort)r;
}
__device__ inline float bf2f(ushort h) { return __uint_as_float(((unsigned)h) << 16); }

// ---------------------------------------------------------------- spectral norm, parallel 3-stage (fp64)
struct SnMeta { const float* w[12]; int O[12]; int M[12]; };
struct SnVMap { short mat[68]; short blk[68]; };

// stage 1: v_m = (sum_o W[o,m]) * u0 ; accumulate ||v||^2
DEV void snv_kernel(SnMeta a, SnVMap mp, double* __restrict__ vbuf, double* __restrict__ vnorm2) {
    int b = blockIdx.x;
    int id = mp.mat[b];
    int m = mp.blk[b] * 256 + threadIdx.x;
    int O = a.O[id], M = a.M[id];
    const float* W = a.w[id];
    __shared__ double red[256];
    double ps = 0.0;
    if (m < M) {
        double s = 0.0;
        for (int o = 0; o < O; ++o) s += (double)W[(size_t)o * M + m];
        s *= 1.0 / sqrt((double)O);
        vbuf[id * 2304 + m] = s;
        ps = s * s;
    }
    red[threadIdx.x] = ps; __syncthreads();
    for (int st = 128; st > 0; st >>= 1) { if (threadIdx.x < st) red[threadIdx.x] += red[threadIdx.x + st]; __syncthreads(); }
    if (threadIdx.x == 0) atomicAdd(vnorm2 + id, red[0]);
}

// stage 2: per row o (one wave): u2_o = (W[o,:]  . v) / ||v|| ; accumulate ||u2||^2
DEV void snu_kernel(SnMeta a, const double* __restrict__ vbuf,
                    const double* __restrict__ vnorm2, double* __restrict__ unorm2) {
    int wv = blockIdx.x * 4 + (threadIdx.x >> 6);
    int lane = threadIdx.x & 63;
    const int cumR[13] = {0, 256, 512, 768, 1024, 1280, 1536, 1792, 2048, 2304, 2560, 2561, 2661};
    if (wv >= 2661) return;
    int id = 0;
    for (int i = 0; i < 12; ++i) if (wv >= cumR[i]) id = i;
    int o = wv - cumR[id];
    int M = a.M[id];
    const float* Wr = a.w[id] + (size_t)o * M;
    const double* vb = vbuf + id * 2304;
    double s = 0.0;
    for (int m = lane; m < M; m += 64) s += (double)Wr[m] * vb[m];
    for (int off = 32; off > 0; off >>= 1) s += __shfl_down(s, off, 64);
    if (lane == 0) {
        double s1 = 1.0 / (sqrt(vnorm2[id]) + 1e-8);
        double u = s * s1;
        atomicAdd(unorm2 + id, u * u);
    }
}

// stage 3: sigma = ||u2||^2 / (||u2|| + eps)
DEV void snf_kernel(const double* __restrict__ unorm2, float* __restrict__ sig) {
    int t = threadIdx.x;
    if (t < 12) {
        double n2 = unorm2[t];
        sig[t] = (float)(n2 / (sqrt(n2) + 1e-8));
    }
}

// ---------------------------------------------------------------- weight prep: w/sigma -> split bf16 [tap][icc][oc][32ic], hi+lo planes
struct PrepArgs { const float* w[8]; int C[8]; int sigidx[8]; int outoff[8]; int nel[8]; };

DEV void prep_kernel(PrepArgs a, const float* __restrict__ sig, ushort* __restrict__ wp) {
    int gid = blockIdx.x * 256 + threadIdx.x;
    int L = 0, cum = 0;
    for (int i = 0; i < 8; ++i) { if (gid >= cum && gid < cum + a.nel[i]) { L = i; break; } cum += a.nel[i]; }
    if (gid >= cum + a.nel[L]) return;
    int e = gid - cum;
    int C = a.C[L];
    int NICC = (C + 31) >> 5;
    int icl = e & 31;
    int oc = (e >> 5) & 255;
    int icc = (e >> 13) % NICC;
    int tap = e / (8192 * NICC);
    int ic = icc * 32 + icl;
    float v = 0.f;
    if (ic < C) v = a.w[L][((size_t)oc * C + ic) * 9 + tap] / sig[a.sigidx[L]];
    ushort h = f2bf(v);
    ushort l = f2bf(v - bf2f(h));
    wp[a.outoff[L] + e] = h;
    wp[a.outoff[L] + a.nel[L] + e] = l;
}

// ---------------------------------------------------------------- MFMA implicit-GEMM 3x3 conv, pad 1
template<int ST, int NTW, int NICC, bool RELU, bool POOL, bool RES, bool INS, bool OUTS>
DEV void conv_mfma(const float* __restrict__ in, const ushort* __restrict__ inhi,
                   const ushort* __restrict__ inlo, const ushort* __restrict__ wp,
                   const float* __restrict__ bias, const float* __restrict__ res,
                   float* __restrict__ out, ushort* __restrict__ outhi, ushort* __restrict__ outlo,
                   int C, int H) {
    const int MT = ST * 4;
    const int PLANE = NICC * 73728;           // 9*NICC*256*32
    __shared__ ushort sH[ST * 100 * 40];
    __shared__ ushort sL[ST * 100 * 40];
    int t = threadIdx.x;
    int wid = t >> 6, lane = t & 63, quad = lane >> 4, l15 = lane & 15;
    int n = blockIdx.z;
    int ocb = blockIdx.y * (NTW * 64) + wid * (NTW * 16);
    int tpr = H >> 3;
    int tIdx0 = blockIdx.x * ST;

    int abase[MT];
    #pragma unroll
    for (int mt = 0; mt < MT; ++mt) {
        int m64 = (mt & 3) * 16 + l15;
        abase[mt] = (((mt >> 2) * 100 + (m64 >> 3) * 10 + (m64 & 7)) * 40) + quad * 8;
    }

    f4v acc[MT][NTW];
    #pragma unroll
    for (int mt = 0; mt < MT; ++mt)
        #pragma unroll
        for (int nt = 0; nt < NTW; ++nt)
            acc[mt][nt] = (f4v){0.f, 0.f, 0.f, 0.f};

    for (int icc = 0; icc < NICC; ++icc) {
        __syncthreads();
        const int NSTAGE = ST * 100 * 32;
        for (int i = t; i < NSTAGE; i += 256) {
            int ic = i / (ST * 100);
            int rr = i - ic * (ST * 100);
            int tile = rr / 100, pos = rr - (rr / 100) * 100;
            int tIdx = tIdx0 + tile;
            int th0 = (tIdx / tpr) * 8, tw0 = (tIdx % tpr) * 8;
            int gy = th0 - 1 + pos / 10, gx = tw0 - 1 + (pos % 10);
            int gic = icc * 32 + ic;
            ushort hv = 0, lv = 0;
            if (gic < C && gy >= 0 && gy < H && gx >= 0 && gx < H) {
                size_t gi = (((size_t)n * C + gic) * H + gy) * H + gx;
                if (INS) { hv = inhi[gi]; lv = inlo[gi]; }
                else {
                    float v = in[gi];
                    if (RELU) v = fmaxf(v, 0.f);
                    hv = f2bf(v);
                    lv = f2bf(v - bf2f(hv));
                }
            }
            int si = (tile * 100 + pos) * 40 + ic;
            sH[si] = hv; sL[si] = lv;
        }
        __syncthreads();
        for (int tap = 0; tap < 9; ++tap) {
            int toff = ((tap / 3) * 10 + (tap % 3)) * 40;
            s8v bh[NTW], bl[NTW];
            size_t wbase = (size_t)(tap * NICC + icc) * 8192;
            #pragma unroll
            for (int nt = 0; nt < NTW; ++nt) {
                size_t wo = wbase + (size_t)(ocb + nt * 16 + l15) * 32 + quad * 8;
                bh[nt] = *(const s8v*)(wp + wo);
                bl[nt] = *(const s8v*)(wp + PLANE + wo);
            }
            #pragma unroll
            for (int mt = 0; mt < MT; ++mt) {
                s8v ah = *(const s8v*)(&sH[abase[mt] + toff]);
                s8v al = *(const s8v*)(&sL[abase[mt] + toff]);
                #pragma unroll
                for (int nt = 0; nt < NTW; ++nt) {
                    acc[mt][nt] = __builtin_amdgcn_mfma_f32_16x16x32_bf16(al, bh[nt], acc[mt][nt], 0, 0, 0);
                    acc[mt][nt] = __builtin_amdgcn_mfma_f32_16x16x32_bf16(ah, bl[nt], acc[mt][nt], 0, 0, 0);
                    acc[mt][nt] = __builtin_amdgcn_mfma_f32_16x16x32_bf16(ah, bh[nt], acc[mt][nt], 0, 0, 0);
                }
            }
        }
    }

    // epilogue: D[m = (mt&3)*16 + quad*4 + r][oc = ocb + nt*16 + l15]
    #pragma unroll
    for (int nt = 0; nt < NTW; ++nt) {
        int oc = ocb + nt * 16 + l15;
        float bv = bias[oc];
        #pragma unroll
        for (int mt = 0; mt < MT; ++mt) {
            int tIdx = tIdx0 + (mt >> 2);
            int th0 = (tIdx / tpr) * 8, tw0 = (tIdx % tpr) * 8;
            if (POOL) {
                float s01 = acc[mt][nt][0] + acc[mt][nt][1];
                float s23 = acc[mt][nt][2] + acc[mt][nt][3];
                float o01 = s01 + __shfl_down(s01, 32, 64);
                float o23 = s23 + __shfl_down(s23, 32, 64);
                if (quad < 2) {
                    int Ho = H >> 1;
                    int oy = (th0 >> 1) + (mt & 3);
                    int ox = (tw0 >> 1) + quad * 2;
                    size_t ob = ((size_t)(n * 256 + oc) * Ho + oy) * Ho;
                    out[ob + ox] = 0.25f * o01 + bv;
                    out[ob + ox + 1] = 0.25f * o23 + bv;
                }
            } else {
                #pragma unroll
                for (int r = 0; r < 4; ++r) {
                    int p16 = quad * 4 + r;
                    int y = th0 + (mt & 3) * 2 + (p16 >> 3);
                    int x = tw0 + (p16 & 7);
                    size_t oi = (((size_t)(n * 256 + oc)) * H + y) * H + x;
                    float v = acc[mt][nt][r] + bv;
                    if (RES) v += res[oi];
                    if (OUTS) {
                        v = fmaxf(v, 0.f);
                        ushort h = f2bf(v);
                        outhi[oi] = h;
                        outlo[oi] = f2bf(v - bf2f(h));
                    } else {
                        out[oi] = v;
                    }
                }
            }
        }
    }
}

// ---------------------------------------------------------------- block-0 shortcut: h1 += conv1x1(pool2(x)) + b
DEV void sc0_kernel(const float* __restrict__ x, const float* __restrict__ wsc,
                    const float* __restrict__ bsc, const float* __restrict__ sig,
                    float* __restrict__ h1) {
    int idx = blockIdx.x * 256 + threadIdx.x;
    int ow = idx & 15, oh = (idx >> 4) & 15, oc = (idx >> 8) & 255, n = idx >> 16;
    float scale = 1.f / sig[0];
    float acc = bsc[oc];
    #pragma unroll
    for (int ic = 0; ic < 3; ++ic) {
        const float* xb = x + (((size_t)(n * 3 + ic)) * 32 + oh * 2) * 32 + ow * 2;
        float pv = 0.25f * (xb[0] + xb[1] + xb[32] + xb[33]);
        acc += pv * (wsc[oc * 3 + ic] * scale);
    }
    h1[idx] += acc;
}

// ---------------------------------------------------------------- block-1 shortcut: h2 += conv1x1(pool2(h1)) + b
DEV void sc1_kernel(const float* __restrict__ h1, const float* __restrict__ wsc,
                    const float* __restrict__ bsc, const float* __restrict__ sig,
                    float* __restrict__ h2) {
    __shared__ float sP[64][64];
    __shared__ float sWs[64][65];
    int t = threadIdx.x;
    int n = blockIdx.x, ocb = blockIdx.y * 64;
    int ocg = t & 15, pgr = t >> 4;
    float scale = 1.f / sig[0];
    float acc[4][4] = {};
    for (int c0 = 0; c0 < 256; c0 += 64) {
        __syncthreads();
        for (int i = t; i < 4096; i += 256) {
            int ic = i >> 6, p = i & 63;
            int oh = p >> 3, ow = p & 7;
            const float* hb = h1 + (((size_t)(n * 256 + c0 + ic)) * 16 + oh * 2) * 16 + ow * 2;
            sP[ic][p] = 0.25f * (hb[0] + hb[1] + hb[16] + hb[17]);
            int oc = i >> 6, ic2 = i & 63;
            sWs[oc][ic2] = wsc[(size_t)(ocb + oc) * 256 + c0 + ic2] * scale;
        }
        __syncthreads();
        for (int ic = 0; ic < 64; ++ic) {
            float pv[4];
            #pragma unroll
            for (int q = 0; q < 4; ++q) pv[q] = sP[ic][pgr * 4 + q];
            #pragma unroll
            for (int j = 0; j < 4; ++j) {
                float wv = sWs[ocg + 16 * j][ic];
                #pragma unroll
                for (int q = 0; q < 4; ++q) acc[j][q] += wv * pv[q];
            }
        }
    }
    #pragma unroll
    for (int j = 0; j < 4; ++j) {
        int oc = ocb + ocg + 16 * j;
        float bv = bsc[oc];
        #pragma unroll
        for (int q = 0; q < 4; ++q) {
            size_t oi = ((size_t)(n * 256 + oc)) * 64 + pgr * 4 + q;
            h2[oi] += acc[j][q] + bv;
        }
    }
}

// ---------------------------------------------------------------- VQ: direct min squared distance, block = 32 pixels x 256 codes
DEV void vq_kernel(const float* __restrict__ h, const float* __restrict__ cb,
                   unsigned long long* __restrict__ mb, int HW) {
    __shared__ float sX[256][32];
    __shared__ float sE[64][64];
    __shared__ float sRV[32][16];
    __shared__ int   sRK[32][16];
    int t = threadIdx.x;
    int pix0 = blockIdx.x * 32;
    int k00 = blockIdx.y * 256;
    int n = pix0 / HW, s0 = pix0 % HW;
    const float* hb = h + (size_t)n * 256 * HW + s0;
    for (int i = t; i < 8192; i += 256) { int c = i >> 5, p = i & 31; sX[c][p] = hb[(size_t)c * HW + p]; }
    int pg = t >> 4, kg = t & 15;
    int p0 = pg * 2, p1 = p0 + 1;
    float bv0 = 3.0e38f, bv1 = 3.0e38f; int bk0 = 0, bk1 = 0;
    for (int k0 = 0; k0 < 4; ++k0) {
        float a0[4] = {}, a1[4] = {};
        for (int c0 = 0; c0 < 4; ++c0) {
            __syncthreads();
            for (int i = t; i < 4096; i += 256) {
                int c = i >> 6, k = i & 63;
                sE[c][k] = cb[(size_t)(c0 * 64 + c) * 1024 + k00 + k0 * 64 + k];
            }
            __syncthreads();
            #pragma unroll 4
            for (int c = 0; c < 64; ++c) {
                float x0 = sX[c0 * 64 + c][p0], x1 = sX[c0 * 64 + c][p1];
                #pragma unroll
                for (int j = 0; j < 4; ++j) {
                    float e = sE[c][kg * 4 + j];
                    float d0 = x0 - e, d1 = x1 - e;
                    a0[j] += d0 * d0;
                    a1[j] += d1 * d1;
                }
            }
        }
        #pragma unroll
        for (int j = 0; j < 4; ++j) {
            int k = k00 + k0 * 64 + kg * 4 + j;
            if (a0[j] < bv0) { bv0 = a0[j]; bk0 = k; }
            if (a1[j] < bv1) { bv1 = a1[j]; bk1 = k; }
        }
    }
    sRV[p0][kg] = bv0; sRK[p0][kg] = bk0;
    sRV[p1][kg] = bv1; sRK[p1][kg] = bk1;
    __syncthreads();
    if (t < 32) {
        float bv = 3.0e38f; int bk = 0;
        for (int kk = 0; kk < 16; ++kk) {
            float v = sRV[t][kk]; int k = sRK[t][kk];
            if (v < bv || (v == bv && k < bk)) { bv = v; bk = k; }
        }
        unsigned long long pk = ((unsigned long long)__float_as_uint(bv) << 32) | (unsigned)bk;
        atomicMin(mb + pix0 + t, pk);
    }
}

DEV void vq_finalize(const unsigned long long* __restrict__ mb,
                     float* __restrict__ dacc, int* __restrict__ hist) {
    int gid = blockIdx.x * 256 + threadIdx.x;   // 0..28671
    unsigned long long pk = mb[gid];
    float bv = __uint_as_float((unsigned)(pk >> 32));
    int k = (int)(unsigned)(pk & 0xFFFFFFFFu);
    int layer, n;
    if (gid < 16384) { layer = 0; n = gid >> 8; }
    else { int r = gid - 16384; layer = 1 + r / 4096; n = (r & 4095) >> 6; }
    atomicAdd(dacc + layer * 64 + n, bv);
    if (gid >= 24576) atomicAdd(hist + k, 1);
}

// ---------------------------------------------------------------- head + ppl
DEV void head_kernel(const float* __restrict__ h4, const float* __restrict__ lin_w,
                     const float* __restrict__ lin_b, const float* __restrict__ emb_w,
                     const int* __restrict__ y, const float* __restrict__ sig,
                     const float* __restrict__ dacc, float* __restrict__ out) {
    __shared__ double r1[256], r2[256];
    int b = blockIdx.x, t = threadIdx.x;
    const float* hb = h4 + ((size_t)b * 256 + t) * 64;
    float s = 0.f;
    #pragma unroll 4
    for (int i = 0; i < 64; ++i) s += fmaxf(hb[i], 0.f);
    int yb = y[b];
    r1[t] = (double)s * (double)lin_w[t];
    r2[t] = (double)s * (double)emb_w[(size_t)yb * 256 + t];
    __syncthreads();
    for (int st = 128; st > 0; st >>= 1) { if (t < st) { r1[t] += r1[t + st]; r2[t] += r2[t + st]; } __syncthreads(); }
    if (t == 0) {
        out[b] = (float)(r1[0] / (double)sig[10] + (double)lin_b[0] + r2[0] / (double)sig[11]);
        out[64 + b] = (float)(0.5 * ((double)dacc[b] * (1.0 / 65536.0)
                              + ((double)dacc[64 + b] + (double)dacc[128 + b] + (double)dacc[192 + b]) * (1.0 / 16384.0)));
    }
}

DEV void ppl_kernel(const int* __restrict__ hist, float* __restrict__ outp) {
    __shared__ double red[256];
    int t = threadIdx.x;
    double s = 0.0;
    for (int k = t; k < 1024; k += 256) {
        double p = (double)hist[k] * (1.0 / 4096.0);
        s += p * log(p + 1e-10);
    }
    red[t] = s; __syncthreads();
    for (int st = 128; st > 0; st >>= 1) { if (t < st) red[t] += red[t + st]; __syncthreads(); }
    if (t == 0) outp[0] = (float)exp(-red[0]);
}

// ---------------------------------------------------------------- launch
extern "C" void kernel_launch(void* const* d_in, const int* in_sizes, int n_in,
                              void* d_out, int out_size, void* d_ws, size_t ws_size,
                              hipStream_t stream) {
    (void)in_sizes; (void)n_in; (void)out_size; (void)ws_size;
    const float* x      = (const float*)d_in[0];
    const int*   y      = (const int*)  d_in[1];
    const float* b0_w1  = (const float*)d_in[2];
    const float* b0_b1  = (const float*)d_in[3];
    const float* b0_w2  = (const float*)d_in[4];
    const float* b0_b2  = (const float*)d_in[5];
    const float* b0_wsc = (const float*)d_in[6];
    const float* b0_bsc = (const float*)d_in[7];
    const float* b1_w1  = (const float*)d_in[8];
    const float* b1_b1  = (const float*)d_in[9];
    const float* b1_w2  = (const float*)d_in[10];
    const float* b1_b2  = (const float*)d_in[11];
    const float* b1_wsc = (const float*)d_in[12];
    const float* b1_bsc = (const float*)d_in[13];
    const float* b2_w1  = (const float*)d_in[14];
    const float* b2_b1  = (const float*)d_in[15];
    const float* b2_w2  = (const float*)d_in[16];
    const float* b2_b2  = (const float*)d_in[17];
    const float* b3_w1  = (const float*)d_in[18];
    const float* b3_b1  = (const float*)d_in[19];
    const float* b3_w2  = (const float*)d_in[20];
    const float* b3_b2  = (const float*)d_in[21];
    const float* cb0    = (const float*)d_in[22];
    const float* cb1    = (const float*)d_in[23];
    const float* cb2    = (const float*)d_in[24];
    const float* cb3    = (const float*)d_in[25];
    const float* lin_w  = (const float*)d_in[26];
    const float* lin_b  = (const float*)d_in[27];
    const float* emb_w  = (const float*)d_in[28];
    float* out = (float*)d_out;

    // ---- workspace map (floats, NO overlaps except tb/t2 in dead-A region) ----
    float* wsf  = (float*)d_ws;
    float* sig  = wsf;                                           // [0,16)
    float* dacc = wsf + 16;                                      // [16,272)
    double* vnorm2 = (double*)(wsf + 512);                       // 12 dbl [512,536)
    double* unorm2 = (double*)(wsf + 544);                       // 12 dbl [544,568)
    int*   hist = (int*)(wsf + 1296);                            // [1296,2320) ints
    unsigned long long* mb = (unsigned long long*)(wsf + 4096);  // 28672 u64 -> [4096,61440)
    ushort* Ahi = (ushort*)(wsf + 65536);                        // [65536,8454144) f
    ushort* Alo = Ahi + 16777216;                                // [8454144,16842752) f
    float* h1 = wsf + 16842752;                                  // [16842752,21037056)
    float* h2 = h1 + 4194304;                                    // [21037056,22085632)
    float* h3 = h2 + 1048576;                                    // [22085632,23134208)
    float* h4 = h3 + 1048576;                                    // [23134208,24182784)
    float* tb = wsf + 65536;                                     // aliases dead A (after conv0_2)
    float* t2 = wsf + 65536 + 4194304;                           // aliases dead A
    ushort* wp = (ushort*)(wsf + 24182784);                      // 8404992 ush -> ends f 28385280
    double* vbuf = (double*)(wsf + 28385280);                    // 12*2304 dbl -> ends f 28440576

    hipMemsetAsync(dacc, 0, 256 * sizeof(float), stream);
    hipMemsetAsync(wsf + 512, 0, 256, stream);                   // vnorm2 + unorm2
    hipMemsetAsync(hist, 0, 1024 * sizeof(int), stream);
    hipMemsetAsync(mb, 0xFF, 28672 * sizeof(unsigned long long), stream);

    SnMeta sm;
    const float* sw[12] = {b0_w1, b0_w2, b0_wsc, b1_w1, b1_w2, b1_wsc,
                           b2_w1, b2_w2, b3_w1, b3_w2, lin_w, emb_w};
    int sO[12] = {256, 256, 256, 256, 256, 256, 256, 256, 256, 256, 1, 100};
    int sM[12] = {27, 2304, 3, 2304, 2304, 256, 2304, 2304, 2304, 2304, 256, 256};
    for (int i = 0; i < 12; ++i) { sm.w[i] = sw[i]; sm.O[i] = sO[i]; sm.M[i] = sM[i]; }
    SnVMap mp;
    {
        int bi = 0;
        for (int i = 0; i < 12; ++i) {
            int nb = (sM[i] + 255) / 256;
            for (int j = 0; j < nb; ++j) { mp.mat[bi] = (short)i; mp.blk[bi] = (short)j; ++bi; }
        }
        // bi == 68
    }
    snv_kernel<<<68, 256, 0, stream>>>(sm, mp, vbuf, vnorm2);
    snu_kernel<<<666, 256, 0, stream>>>(sm, vbuf, vnorm2, unorm2);
    snf_kernel<<<1, 64, 0, stream>>>(unorm2, sig);

    PrepArgs pa;
    const float* pw[8] = {b0_w1, b0_w2, b1_w1, b1_w2, b2_w1, b2_w2, b3_w1, b3_w2};
    int pC[8]   = {3, 256, 256, 256, 256, 256, 256, 256};
    int pS[8]   = {0, 1, 3, 4, 6, 7, 8, 9};
    int pOff[8] = {0, 147456, 1327104, 2506752, 3686400, 4866048, 6045696, 7225344};
    int pN[8]   = {73728, 589824, 589824, 589824, 589824, 589824, 589824, 589824};
    for (int i = 0; i < 8; ++i) { pa.w[i] = pw[i]; pa.C[i] = pC[i]; pa.sigidx[i] = pS[i]; pa.outoff[i] = pOff[i]; pa.nel[i] = pN[i]; }
    prep_kernel<<<16416, 256, 0, stream>>>(pa, sig, wp);

    // block 0: conv0_1 (x, no relu-in, split-out) -> conv0_2 (split-in, pool) ; sc0 ; vq0
    conv_mfma<2, 4, 1, false, false, false, false, true><<<dim3(8, 1, 64), 256, 0, stream>>>(
        x, nullptr, nullptr, wp + 0, b0_b1, nullptr, nullptr, Ahi, Alo, 3, 32);
    conv_mfma<2, 4, 8, true, true, false, true, false><<<dim3(8, 1, 64), 256, 0, stream>>>(
        nullptr, Ahi, Alo, wp + 147456, b0_b2, nullptr, h1, nullptr, nullptr, 256, 32);
    sc0_kernel<<<16384, 256, 0, stream>>>(x, b0_wsc, b0_bsc, sig + 2, h1);
    vq_kernel<<<dim3(512, 4), 256, 0, stream>>>(h1, cb0, mb + 0, 256);

    // block 1
    conv_mfma<2, 2, 8, true, false, false, false, false><<<dim3(2, 2, 64), 256, 0, stream>>>(
        h1, nullptr, nullptr, wp + 1327104, b1_b1, nullptr, tb, nullptr, nullptr, 256, 16);
    conv_mfma<2, 2, 8, true, true, false, false, false><<<dim3(2, 2, 64), 256, 0, stream>>>(
        tb, nullptr, nullptr, wp + 2506752, b1_b2, nullptr, h2, nullptr, nullptr, 256, 16);
    sc1_kernel<<<dim3(64, 4), 256, 0, stream>>>(h1, b1_wsc, b1_bsc, sig + 5, h2);
    vq_kernel<<<dim3(128, 4), 256, 0, stream>>>(h2, cb1, mb + 16384, 64);

    // block 2 (identity sc: residual in conv2_2 epilogue)
    conv_mfma<1, 1, 8, true, false, false, false, false><<<dim3(1, 4, 64), 256, 0, stream>>>(
        h2, nullptr, nullptr, wp + 3686400, b2_b1, nullptr, t2, nullptr, nullptr, 256, 8);
    conv_mfma<1, 1, 8, true, false, true, false, false><<<dim3(1, 4, 64), 256, 0, stream>>>(
        t2, nullptr, nullptr, wp + 4866048, b2_b2, h2, h3, nullptr, nullptr, 256, 8);
    vq_kernel<<<dim3(128, 4), 256, 0, stream>>>(h3, cb2, mb + 20480, 64);

    // block 3
    conv_mfma<1, 1, 8, true, false, false, false, false><<<dim3(1, 4, 64), 256, 0, stream>>>(
        h3, nullptr, nullptr, wp + 6045696, b3_b1, nullptr, t2, nullptr, nullptr, 256, 8);
    conv_mfma<1, 1, 8, true, false, true, false, false><<<dim3(1, 4, 64), 256, 0, stream>>>(
        t2, nullptr, nullptr, wp + 7225344, b3_b2, h3, h4, nullptr, nullptr, 256, 8);
    vq_kernel<<<dim3(128, 4), 256, 0, stream>>>(h4, cb3, mb + 24576, 64);

    vq_finalize<<<112, 256, 0, stream>>>(mb, dacc, hist);
    head_kernel<<<64, 256, 0, stream>>>(h4, lin_w, lin_b, emb_w, y, sig, dacc, out);
    ppl_kernel<<<1, 256, 0, stream>>>(hist, out + 128);
}

// Round 7
// 1699.268 us; speedup vs baseline: 3.6178x; 1.1349x over previous
//
#include <hip/hip_runtime.h>
#include <math.h>

typedef __attribute__((ext_vector_type(8))) short s8v;   // 8 bf16
typedef __attribute__((ext_vector_type(4))) float f4v;   // mfma acc

__device__ inline ushort f2bf(float x) {
    unsigned u = __float_as_uint(x);
    unsigned r = (u + 0x7FFFu + ((u >> 16) & 1u)) >> 16;   // RNE
    return (ushort)r;
}
__device__ inline float bf2f(ushort h) { return __uint_as_float(((unsigned)h) << 16); }

#define DEV __global__ __launch_bounds__(256)

// ---------------------------------------------------------------- spectral norm, parallel 3-stage (fp64)
struct SnMeta { const float* w[12]; int O[12]; int M[12]; };
struct SnVMap { short mat[68]; short blk[68]; };

DEV void snv_kernel(SnMeta a, SnVMap mp, double* __restrict__ vbuf, double* __restrict__ vnorm2) {
    int b = blockIdx.x;
    int id = mp.mat[b];
    int m = mp.blk[b] * 256 + threadIdx.x;
    int O = a.O[id], M = a.M[id];
    const float* W = a.w[id];
    __shared__ double red[256];
    double ps = 0.0;
    if (m < M) {
        double s = 0.0;
        for (int o = 0; o < O; ++o) s += (double)W[(size_t)o * M + m];
        s *= 1.0 / sqrt((double)O);
        vbuf[id * 2304 + m] = s;
        ps = s * s;
    }
    red[threadIdx.x] = ps; __syncthreads();
    for (int st = 128; st > 0; st >>= 1) { if (threadIdx.x < st) red[threadIdx.x] += red[threadIdx.x + st]; __syncthreads(); }
    if (threadIdx.x == 0) atomicAdd(vnorm2 + id, red[0]);
}

DEV void snu_kernel(SnMeta a, const double* __restrict__ vbuf,
                    const double* __restrict__ vnorm2, double* __restrict__ unorm2) {
    int wv = blockIdx.x * 4 + (threadIdx.x >> 6);
    int lane = threadIdx.x & 63;
    const int cumR[13] = {0, 256, 512, 768, 1024, 1280, 1536, 1792, 2048, 2304, 2560, 2561, 2661};
    if (wv >= 2661) return;
    int id = 0;
    for (int i = 0; i < 12; ++i) if (wv >= cumR[i]) id = i;
    int o = wv - cumR[id];
    int M = a.M[id];
    const float* Wr = a.w[id] + (size_t)o * M;
    const double* vb = vbuf + id * 2304;
    double s = 0.0;
    for (int m = lane; m < M; m += 64) s += (double)Wr[m] * vb[m];
    for (int off = 32; off > 0; off >>= 1) s += __shfl_down(s, off, 64);
    if (lane == 0) {
        double s1 = 1.0 / (sqrt(vnorm2[id]) + 1e-8);
        double u = s * s1;
        atomicAdd(unorm2 + id, u * u);
    }
}

DEV void snf_kernel(const double* __restrict__ unorm2, float* __restrict__ sig) {
    int t = threadIdx.x;
    if (t < 12) {
        double n2 = unorm2[t];
        sig[t] = (float)(n2 / (sqrt(n2) + 1e-8));
    }
}

// ---------------------------------------------------------------- weight prep: w/sigma -> split bf16 [tap][icc][oc][32ic], hi+lo planes
struct PrepArgs { const float* w[8]; int C[8]; int sigidx[8]; int outoff[8]; int nel[8]; };

DEV void prep_kernel(PrepArgs a, const float* __restrict__ sig, ushort* __restrict__ wp) {
    int gid = blockIdx.x * 256 + threadIdx.x;
    int L = 0, cum = 0;
    for (int i = 0; i < 8; ++i) { if (gid >= cum && gid < cum + a.nel[i]) { L = i; break; } cum += a.nel[i]; }
    if (gid >= cum + a.nel[L]) return;
    int e = gid - cum;
    int C = a.C[L];
    int NICC = (C + 31) >> 5;
    int icl = e & 31;
    int oc = (e >> 5) & 255;
    int icc = (e >> 13) % NICC;
    int tap = e / (8192 * NICC);
    int ic = icc * 32 + icl;
    float v = 0.f;
    if (ic < C) v = a.w[L][((size_t)oc * C + ic) * 9 + tap] / sig[a.sigidx[L]];
    ushort h = f2bf(v);
    ushort l = f2bf(v - bf2f(h));
    wp[a.outoff[L] + e] = h;
    wp[a.outoff[L] + a.nel[L] + e] = l;
}

// ---------------------------------------------------------------- MFMA implicit-GEMM 3x3 conv, pad 1
// A in LDS [tile*100+pos][hi32|lo32] stride 72 (2-way bank alias = free).
// INS/OUTS tensors use NHWC-split-64: ushort idx = (((n*H+y)*H+x)*8 + iccg)*64 + (lo?32:0) + (oc&31).
// B weights prefetched double-buffered across taps (hides L2 latency).
template<int ST, int NW, int NTW, int NICC, bool RELU, bool POOL, bool RES, bool INS, bool OUTS>
__global__ __launch_bounds__(NW * 64) void conv_mfma(
        const float* __restrict__ in, const ushort* __restrict__ ins,
        const ushort* __restrict__ wp, const float* __restrict__ bias,
        const float* __restrict__ res, float* __restrict__ out,
        ushort* __restrict__ outs, int C, int H) {
    const int MT = ST * 4;
    const int PLANE = NICC * 73728;           // 9*NICC*256*32
    __shared__ ushort sA[ST * 100 * 72];
    int t = threadIdx.x;
    int wid = t >> 6, lane = t & 63, quad = lane >> 4, l15 = lane & 15;
    int n = blockIdx.z;
    int ocb = blockIdx.y * (NW * NTW * 16) + wid * (NTW * 16);
    int tpr = H >> 3;
    int tIdx0 = blockIdx.x * ST;

    int abase[MT];
    #pragma unroll
    for (int mt = 0; mt < MT; ++mt) {
        int m64 = (mt & 3) * 16 + l15;
        abase[mt] = (((mt >> 2) * 100 + (m64 >> 3) * 10 + (m64 & 7)) * 72) + quad * 8;
    }

    f4v acc[MT][NTW];
    #pragma unroll
    for (int mt = 0; mt < MT; ++mt)
        #pragma unroll
        for (int nt = 0; nt < NTW; ++nt)
            acc[mt][nt] = (f4v){0.f, 0.f, 0.f, 0.f};

    for (int icc = 0; icc < NICC; ++icc) {
        __syncthreads();
        if (INS) {
            // vectorized staging: 16B chunks, 8 per pos
            for (int i = t; i < ST * 100 * 8; i += NW * 64) {
                int pg = i >> 3, part = i & 7;
                int tile = pg / 100, pos = pg - tile * 100;
                int tIdx = tIdx0 + tile;
                int th0 = (tIdx / tpr) * 8, tw0 = (tIdx % tpr) * 8;
                int gy = th0 - 1 + pos / 10, gx = tw0 - 1 + (pos % 10);
                s8v v = (s8v){0, 0, 0, 0, 0, 0, 0, 0};
                if (gy >= 0 && gy < H && gx >= 0 && gx < H)
                    v = *(const s8v*)(ins + ((((size_t)n * H + gy) * H + gx) * 8 + icc) * 64 + part * 8);
                *(s8v*)(&sA[(tile * 100 + pos) * 72 + part * 8]) = v;
            }
        } else {
            for (int i = t; i < ST * 100 * 32; i += NW * 64) {
                int ic = i / (ST * 100);
                int rr = i - ic * (ST * 100);
                int tile = rr / 100, pos = rr - (rr / 100) * 100;
                int tIdx = tIdx0 + tile;
                int th0 = (tIdx / tpr) * 8, tw0 = (tIdx % tpr) * 8;
                int gy = th0 - 1 + pos / 10, gx = tw0 - 1 + (pos % 10);
                int gic = icc * 32 + ic;
                ushort hv = 0, lv = 0;
                if (gic < C && gy >= 0 && gy < H && gx >= 0 && gx < H) {
                    float v = in[(((size_t)n * C + gic) * H + gy) * H + gx];
                    if (RELU) v = fmaxf(v, 0.f);
                    hv = f2bf(v);
                    lv = f2bf(v - bf2f(hv));
                }
                int si = (tile * 100 + pos) * 72 + ic;
                sA[si] = hv; sA[si + 32] = lv;
            }
        }
        __syncthreads();

        s8v bh[2][NTW], bl[2][NTW];
        {   // preload tap 0
            size_t wb = (size_t)(0 * NICC + icc) * 8192;
            #pragma unroll
            for (int nt = 0; nt < NTW; ++nt) {
                size_t wo = wb + (size_t)(ocb + nt * 16 + l15) * 32 + quad * 8;
                bh[0][nt] = *(const s8v*)(wp + wo);
                bl[0][nt] = *(const s8v*)(wp + PLANE + wo);
            }
        }
        #pragma unroll
        for (int tap = 0; tap < 9; ++tap) {
            int cb = tap & 1;
            if (tap < 8) {   // prefetch next tap's B while this tap's MFMAs run
                size_t wb = (size_t)((tap + 1) * NICC + icc) * 8192;
                #pragma unroll
                for (int nt = 0; nt < NTW; ++nt) {
                    size_t wo = wb + (size_t)(ocb + nt * 16 + l15) * 32 + quad * 8;
                    bh[(tap + 1) & 1][nt] = *(const s8v*)(wp + wo);
                    bl[(tap + 1) & 1][nt] = *(const s8v*)(wp + PLANE + wo);
                }
            }
            int toff = ((tap / 3) * 10 + (tap % 3)) * 72;
            #pragma unroll
            for (int mt = 0; mt < MT; ++mt) {
                s8v ah = *(const s8v*)(&sA[abase[mt] + toff]);
                s8v al = *(const s8v*)(&sA[abase[mt] + toff + 32]);
                #pragma unroll
                for (int nt = 0; nt < NTW; ++nt) {
                    acc[mt][nt] = __builtin_amdgcn_mfma_f32_16x16x32_bf16(al, bh[cb][nt], acc[mt][nt], 0, 0, 0);
                    acc[mt][nt] = __builtin_amdgcn_mfma_f32_16x16x32_bf16(ah, bl[cb][nt], acc[mt][nt], 0, 0, 0);
                    acc[mt][nt] = __builtin_amdgcn_mfma_f32_16x16x32_bf16(ah, bh[cb][nt], acc[mt][nt], 0, 0, 0);
                }
            }
        }
    }

    // epilogue: D[m64 = (mt&3)*16 + quad*4 + r][oc = ocb + nt*16 + l15]
    #pragma unroll
    for (int nt = 0; nt < NTW; ++nt) {
        int oc = ocb + nt * 16 + l15;
        float bv = bias[oc];
        #pragma unroll
        for (int mt = 0; mt < MT; ++mt) {
            int tIdx = tIdx0 + (mt >> 2);
            int th0 = (tIdx / tpr) * 8, tw0 = (tIdx % tpr) * 8;
            if (POOL) {
                float s01 = acc[mt][nt][0] + acc[mt][nt][1];
                float s23 = acc[mt][nt][2] + acc[mt][nt][3];
                float o01 = s01 + __shfl_down(s01, 32, 64);
                float o23 = s23 + __shfl_down(s23, 32, 64);
                if (quad < 2) {
                    int Ho = H >> 1;
                    int oy = (th0 >> 1) + (mt & 3);
                    int ox = (tw0 >> 1) + quad * 2;
                    size_t ob = ((size_t)(n * 256 + oc) * Ho + oy) * Ho;
                    out[ob + ox] = 0.25f * o01 + bv;
                    out[ob + ox + 1] = 0.25f * o23 + bv;
                }
            } else if (OUTS) {
                int iccg = oc >> 5, ocw = oc & 31;
                #pragma unroll
                for (int r = 0; r < 4; ++r) {
                    int p16 = quad * 4 + r;
                    int y = th0 + (mt & 3) * 2 + (p16 >> 3);
                    int x = tw0 + (p16 & 7);
                    float v = fmaxf(acc[mt][nt][r] + bv, 0.f);
                    ushort h = f2bf(v);
                    size_t ob = ((((size_t)n * H + y) * H + x) * 8 + iccg) * 64;
                    outs[ob + ocw] = h;
                    outs[ob + 32 + ocw] = f2bf(v - bf2f(h));
                }
            } else {
                #pragma unroll
                for (int r = 0; r < 4; ++r) {
                    int p16 = quad * 4 + r;
                    int y = th0 + (mt & 3) * 2 + (p16 >> 3);
                    int x = tw0 + (p16 & 7);
                    size_t oi = (((size_t)(n * 256 + oc)) * H + y) * H + x;
                    float v = acc[mt][nt][r] + bv;
                    if (RES) v += res[oi];
                    out[oi] = v;
                }
            }
        }
    }
}

// ---------------------------------------------------------------- block-0 shortcut: h1 += conv1x1(pool2(x)) + b
DEV void sc0_kernel(const float* __restrict__ x, const float* __restrict__ wsc,
                    const float* __restrict__ bsc, const float* __restrict__ sig,
                    float* __restrict__ h1) {
    int idx = blockIdx.x * 256 + threadIdx.x;
    int ow = idx & 15, oh = (idx >> 4) & 15, oc = (idx >> 8) & 255, n = idx >> 16;
    float scale = 1.f / sig[0];
    float acc = bsc[oc];
    #pragma unroll
    for (int ic = 0; ic < 3; ++ic) {
        const float* xb = x + (((size_t)(n * 3 + ic)) * 32 + oh * 2) * 32 + ow * 2;
        float pv = 0.25f * (xb[0] + xb[1] + xb[32] + xb[33]);
        acc += pv * (wsc[oc * 3 + ic] * scale);
    }
    h1[idx] += acc;
}

// ---------------------------------------------------------------- block-1 shortcut: h2 += conv1x1(pool2(h1)) + b
DEV void sc1_kernel(const float* __restrict__ h1, const float* __restrict__ wsc,
                    const float* __restrict__ bsc, const float* __restrict__ sig,
                    float* __restrict__ h2) {
    __shared__ float sP[64][64];
    __shared__ float sWs[64][65];
    int t = threadIdx.x;
    int n = blockIdx.x, ocb = blockIdx.y * 64;
    int ocg = t & 15, pgr = t >> 4;
    float scale = 1.f / sig[0];
    float acc[4][4] = {};
    for (int c0 = 0; c0 < 256; c0 += 64) {
        __syncthreads();
        for (int i = t; i < 4096; i += 256) {
            int ic = i >> 6, p = i & 63;
            int oh = p >> 3, ow = p & 7;
            const float* hb = h1 + (((size_t)(n * 256 + c0 + ic)) * 16 + oh * 2) * 16 + ow * 2;
            sP[ic][p] = 0.25f * (hb[0] + hb[1] + hb[16] + hb[17]);
            int oc = i >> 6, ic2 = i & 63;
            sWs[oc][ic2] = wsc[(size_t)(ocb + oc) * 256 + c0 + ic2] * scale;
        }
        __syncthreads();
        for (int ic = 0; ic < 64; ++ic) {
            float pv[4];
            #pragma unroll
            for (int q = 0; q < 4; ++q) pv[q] = sP[ic][pgr * 4 + q];
            #pragma unroll
            for (int j = 0; j < 4; ++j) {
                float wv = sWs[ocg + 16 * j][ic];
                #pragma unroll
                for (int q = 0; q < 4; ++q) acc[j][q] += wv * pv[q];
            }
        }
    }
    #pragma unroll
    for (int j = 0; j < 4; ++j) {
        int oc = ocb + ocg + 16 * j;
        float bv = bsc[oc];
        #pragma unroll
        for (int q = 0; q < 4; ++q) {
            size_t oi = ((size_t)(n * 256 + oc)) * 64 + pgr * 4 + q;
            h2[oi] += acc[j][q] + bv;
        }
    }
}

// ---------------------------------------------------------------- VQ: direct min squared distance, block = 32 pixels x 256 codes
DEV void vq_kernel(const float* __restrict__ h, const float* __restrict__ cb,
                   unsigned long long* __restrict__ mb, int HW) {
    __shared__ float sX[256][32];
    __shared__ float sE[64][64];
    __shared__ float sRV[32][16];
    __shared__ int   sRK[32][16];
    int t = threadIdx.x;
    int pix0 = blockIdx.x * 32;
    int k00 = blockIdx.y * 256;
    int n = pix0 / HW, s0 = pix0 % HW;
    const float* hb = h + (size_t)n * 256 * HW + s0;
    for (int i = t; i < 8192; i += 256) { int c = i >> 5, p = i & 31; sX[c][p] = hb[(size_t)c * HW + p]; }
    int pg = t >> 4, kg = t & 15;
    int p0 = pg * 2, p1 = p0 + 1;
    float bv0 = 3.0e38f, bv1 = 3.0e38f; int bk0 = 0, bk1 = 0;
    for (int k0 = 0; k0 < 4; ++k0) {
        float a0[4] = {}, a1[4] = {};
        for (int c0 = 0; c0 < 4; ++c0) {
            __syncthreads();
            for (int i = t; i < 4096; i += 256) {
                int c = i >> 6, k = i & 63;
                sE[c][k] = cb[(size_t)(c0 * 64 + c) * 1024 + k00 + k0 * 64 + k];
            }
            __syncthreads();
            #pragma unroll 4
            for (int c = 0; c < 64; ++c) {
                float x0 = sX[c0 * 64 + c][p0], x1 = sX[c0 * 64 + c][p1];
                #pragma unroll
                for (int j = 0; j < 4; ++j) {
                    float e = sE[c][kg * 4 + j];
                    float d0 = x0 - e, d1 = x1 - e;
                    a0[j] += d0 * d0;
                    a1[j] += d1 * d1;
                }
            }
        }
        #pragma unroll
        for (int j = 0; j < 4; ++j) {
            int k = k00 + k0 * 64 + kg * 4 + j;
            if (a0[j] < bv0) { bv0 = a0[j]; bk0 = k; }
            if (a1[j] < bv1) { bv1 = a1[j]; bk1 = k; }
        }
    }
    sRV[p0][kg] = bv0; sRK[p0][kg] = bk0;
    sRV[p1][kg] = bv1; sRK[p1][kg] = bk1;
    __syncthreads();
    if (t < 32) {
        float bv = 3.0e38f; int bk = 0;
        for (int kk = 0; kk < 16; ++kk) {
            float v = sRV[t][kk]; int k = sRK[t][kk];
            if (v < bv || (v == bv && k < bk)) { bv = v; bk = k; }
        }
        unsigned long long pk = ((unsigned long long)__float_as_uint(bv) << 32) | (unsigned)bk;
        atomicMin(mb + pix0 + t, pk);
    }
}

DEV void vq_finalize(const unsigned long long* __restrict__ mb,
                     float* __restrict__ dacc, int* __restrict__ hist) {
    int gid = blockIdx.x * 256 + threadIdx.x;   // 0..28671
    unsigned long long pk = mb[gid];
    float bv = __uint_as_float((unsigned)(pk >> 32));
    int k = (int)(unsigned)(pk & 0xFFFFFFFFu);
    int layer, n;
    if (gid < 16384) { layer = 0; n = gid >> 8; }
    else { int r = gid - 16384; layer = 1 + r / 4096; n = (r & 4095) >> 6; }
    atomicAdd(dacc + layer * 64 + n, bv);
    if (gid >= 24576) atomicAdd(hist + k, 1);
}

// ---------------------------------------------------------------- head + ppl
DEV void head_kernel(const float* __restrict__ h4, const float* __restrict__ lin_w,
                     const float* __restrict__ lin_b, const float* __restrict__ emb_w,
                     const int* __restrict__ y, const float* __restrict__ sig,
                     const float* __restrict__ dacc, float* __restrict__ out) {
    __shared__ double r1[256], r2[256];
    int b = blockIdx.x, t = threadIdx.x;
    const float* hb = h4 + ((size_t)b * 256 + t) * 64;
    float s = 0.f;
    #pragma unroll 4
    for (int i = 0; i < 64; ++i) s += fmaxf(hb[i], 0.f);
    int yb = y[b];
    r1[t] = (double)s * (double)lin_w[t];
    r2[t] = (double)s * (double)emb_w[(size_t)yb * 256 + t];
    __syncthreads();
    for (int st = 128; st > 0; st >>= 1) { if (t < st) { r1[t] += r1[t + st]; r2[t] += r2[t + st]; } __syncthreads(); }
    if (t == 0) {
        out[b] = (float)(r1[0] / (double)sig[10] + (double)lin_b[0] + r2[0] / (double)sig[11]);
        out[64 + b] = (float)(0.5 * ((double)dacc[b] * (1.0 / 65536.0)
                              + ((double)dacc[64 + b] + (double)dacc[128 + b] + (double)dacc[192 + b]) * (1.0 / 16384.0)));
    }
}

DEV void ppl_kernel(const int* __restrict__ hist, float* __restrict__ outp) {
    __shared__ double red[256];
    int t = threadIdx.x;
    double s = 0.0;
    for (int k = t; k < 1024; k += 256) {
        double p = (double)hist[k] * (1.0 / 4096.0);
        s += p * log(p + 1e-10);
    }
    red[t] = s; __syncthreads();
    for (int st = 128; st > 0; st >>= 1) { if (t < st) red[t] += red[t + st]; __syncthreads(); }
    if (t == 0) outp[0] = (float)exp(-red[0]);
}

// ---------------------------------------------------------------- launch
extern "C" void kernel_launch(void* const* d_in, const int* in_sizes, int n_in,
                              void* d_out, int out_size, void* d_ws, size_t ws_size,
                              hipStream_t stream) {
    (void)in_sizes; (void)n_in; (void)out_size; (void)ws_size;
    const float* x      = (const float*)d_in[0];
    const int*   y      = (const int*)  d_in[1];
    const float* b0_w1  = (const float*)d_in[2];
    const float* b0_b1  = (const float*)d_in[3];
    const float* b0_w2  = (const float*)d_in[4];
    const float* b0_b2  = (const float*)d_in[5];
    const float* b0_wsc = (const float*)d_in[6];
    const float* b0_bsc = (const float*)d_in[7];
    const float* b1_w1  = (const float*)d_in[8];
    const float* b1_b1  = (const float*)d_in[9];
    const float* b1_w2  = (const float*)d_in[10];
    const float* b1_b2  = (const float*)d_in[11];
    const float* b1_wsc = (const float*)d_in[12];
    const float* b1_bsc = (const float*)d_in[13];
    const float* b2_w1  = (const float*)d_in[14];
    const float* b2_b1  = (const float*)d_in[15];
    const float* b2_w2  = (const float*)d_in[16];
    const float* b2_b2  = (const float*)d_in[17];
    const float* b3_w1  = (const float*)d_in[18];
    const float* b3_b1  = (const float*)d_in[19];
    const float* b3_w2  = (const float*)d_in[20];
    const float* b3_b2  = (const float*)d_in[21];
    const float* cb0    = (const float*)d_in[22];
    const float* cb1    = (const float*)d_in[23];
    const float* cb2    = (const float*)d_in[24];
    const float* cb3    = (const float*)d_in[25];
    const float* lin_w  = (const float*)d_in[26];
    const float* lin_b  = (const float*)d_in[27];
    const float* emb_w  = (const float*)d_in[28];
    float* out = (float*)d_out;

    // ---- workspace map (float indices) ----
    float* wsf  = (float*)d_ws;
    float* sig  = wsf;                                           // [0,16)
    float* dacc = wsf + 16;                                      // [16,272)
    double* vnorm2 = (double*)(wsf + 512);                       // [512,536)
    double* unorm2 = (double*)(wsf + 544);                       // [544,568)
    int*   hist = (int*)(wsf + 1296);                            // [1296,2320) ints
    unsigned long long* mb = (unsigned long long*)(wsf + 4096);  // [4096,61440)
    ushort* Aus  = (ushort*)(wsf + 65536);                       // 33.5M ush = [65536,16842752) f  (conv0_1 out, NHWC-split)
    ushort* tbus = (ushort*)(wsf + 65536);                       // 8.4M ush -> f [65536,4259840)   (aliases dead A)
    ushort* t2us = (ushort*)(wsf + 4259840);                     // 2.1M ush -> f [4259840,5308416) (aliases dead A)
    float* h1 = wsf + 16842752;                                  // [16842752,21037056)
    float* h2 = h1 + 4194304;                                    // [21037056,22085632)
    float* h3 = h2 + 1048576;                                    // [22085632,23134208)
    float* h4 = h3 + 1048576;                                    // [23134208,24182784)
    ushort* wp = (ushort*)(wsf + 24182784);                      // 8404992 ush -> ends f 28385280
    double* vbuf = (double*)(wsf + 28385280);                    // 12*2304 dbl -> ends f 28440576

    hipMemsetAsync(dacc, 0, 256 * sizeof(float), stream);
    hipMemsetAsync(wsf + 512, 0, 256, stream);                   // vnorm2 + unorm2
    hipMemsetAsync(hist, 0, 1024 * sizeof(int), stream);
    hipMemsetAsync(mb, 0xFF, 28672 * sizeof(unsigned long long), stream);

    SnMeta sm;
    const float* sw[12] = {b0_w1, b0_w2, b0_wsc, b1_w1, b1_w2, b1_wsc,
                           b2_w1, b2_w2, b3_w1, b3_w2, lin_w, emb_w};
    int sO[12] = {256, 256, 256, 256, 256, 256, 256, 256, 256, 256, 1, 100};
    int sM[12] = {27, 2304, 3, 2304, 2304, 256, 2304, 2304, 2304, 2304, 256, 256};
    for (int i = 0; i < 12; ++i) { sm.w[i] = sw[i]; sm.O[i] = sO[i]; sm.M[i] = sM[i]; }
    SnVMap mp;
    {
        int bi = 0;
        for (int i = 0; i < 12; ++i) {
            int nb = (sM[i] + 255) / 256;
            for (int j = 0; j < nb; ++j) { mp.mat[bi] = (short)i; mp.blk[bi] = (short)j; ++bi; }
        }
    }
    snv_kernel<<<68, 256, 0, stream>>>(sm, mp, vbuf, vnorm2);
    snu_kernel<<<666, 256, 0, stream>>>(sm, vbuf, vnorm2, unorm2);
    snf_kernel<<<1, 64, 0, stream>>>(unorm2, sig);

    PrepArgs pa;
    const float* pw[8] = {b0_w1, b0_w2, b1_w1, b1_w2, b2_w1, b2_w2, b3_w1, b3_w2};
    int pC[8]   = {3, 256, 256, 256, 256, 256, 256, 256};
    int pS[8]   = {0, 1, 3, 4, 6, 7, 8, 9};
    int pOff[8] = {0, 147456, 1327104, 2506752, 3686400, 4866048, 6045696, 7225344};
    int pN[8]   = {73728, 589824, 589824, 589824, 589824, 589824, 589824, 589824};
    for (int i = 0; i < 8; ++i) { pa.w[i] = pw[i]; pa.C[i] = pC[i]; pa.sigidx[i] = pS[i]; pa.outoff[i] = pOff[i]; pa.nel[i] = pN[i]; }
    prep_kernel<<<16416, 256, 0, stream>>>(pa, sig, wp);

    // block 0: conv0_1 (x fp32 -> A split-NHWC, relu at write) -> conv0_2 (INS, pool -> h1 fp32)
    conv_mfma<2, 4, 2, 1, false, false, false, false, true><<<dim3(8, 2, 64), 256, 0, stream>>>(
        x, nullptr, wp + 0, b0_b1, nullptr, nullptr, Aus, 3, 32);
    conv_mfma<2, 4, 2, 8, false, true, false, true, false><<<dim3(8, 2, 64), 256, 0, stream>>>(
        nullptr, Aus, wp + 147456, b0_b2, nullptr, h1, nullptr, 256, 32);
    sc0_kernel<<<16384, 256, 0, stream>>>(x, b0_wsc, b0_bsc, sig + 2, h1);
    vq_kernel<<<dim3(512, 4), 256, 0, stream>>>(h1, cb0, mb + 0, 256);

    // block 1 (preact): conv1_1 (relu(h1) -> tb split-NHWC) -> conv1_2 (INS, pool -> h2)
    conv_mfma<2, 4, 1, 8, true, false, false, false, true><<<dim3(2, 4, 64), 256, 0, stream>>>(
        h1, nullptr, wp + 1327104, b1_b1, nullptr, nullptr, tbus, 256, 16);
    conv_mfma<2, 4, 1, 8, false, true, false, true, false><<<dim3(2, 4, 64), 256, 0, stream>>>(
        nullptr, tbus, wp + 2506752, b1_b2, nullptr, h2, nullptr, 256, 16);
    sc1_kernel<<<dim3(64, 4), 256, 0, stream>>>(h1, b1_wsc, b1_bsc, sig + 5, h2);
    vq_kernel<<<dim3(128, 4), 256, 0, stream>>>(h2, cb1, mb + 16384, 64);

    // block 2 (identity sc): conv2_1 (relu(h2) -> t2 split) -> conv2_2 (INS -> h3, +h2)
    conv_mfma<1, 2, 1, 8, true, false, false, false, true><<<dim3(1, 8, 64), 128, 0, stream>>>(
        h2, nullptr, wp + 3686400, b2_b1, nullptr, nullptr, t2us, 256, 8);
    conv_mfma<1, 2, 1, 8, false, false, true, true, false><<<dim3(1, 8, 64), 128, 0, stream>>>(
        nullptr, t2us, wp + 4866048, b2_b2, h2, h3, nullptr, 256, 8);
    vq_kernel<<<dim3(128, 4), 256, 0, stream>>>(h3, cb2, mb + 20480, 64);

    // block 3
    conv_mfma<1, 2, 1, 8, true, false, false, false, true><<<dim3(1, 8, 64), 128, 0, stream>>>(
        h3, nullptr, wp + 6045696, b3_b1, nullptr, nullptr, t2us, 256, 8);
    conv_mfma<1, 2, 1, 8, false, false, true, true, false><<<dim3(1, 8, 64), 128, 0, stream>>>(
        nullptr, t2us, wp + 7225344, b3_b2, h3, h4, nullptr, 256, 8);
    vq_kernel<<<dim3(128, 4), 256, 0, stream>>>(h4, cb3, mb + 24576, 64);

    vq_finalize<<<112, 256, 0, stream>>>(mb, dacc, hist);
    head_kernel<<<64, 256, 0, stream>>>(h4, lin_w, lin_b, emb_w, y, sig, dacc, out);
    ppl_kernel<<<1, 256, 0, stream>>>(hist, out + 128);
}

// Round 8
// 1466.622 us; speedup vs baseline: 4.1917x; 1.1586x over previous
//
#include <hip/hip_runtime.h>
#include <math.h>

typedef __attribute__((ext_vector_type(8))) short s8v;   // 8 bf16
typedef __attribute__((ext_vector_type(4))) float f4v;   // mfma acc

__device__ inline ushort f2bf(float x) {
    unsigned u = __float_as_uint(x);
    unsigned r = (u + 0x7FFFu + ((u >> 16) & 1u)) >> 16;   // RNE
    return (ushort)r;
}
__device__ inline float bf2f(ushort h) { return __uint_as_float(((unsigned)h) << 16); }

#define DEV __global__ __launch_bounds__(256)

// ---------------------------------------------------------------- spectral norm, parallel 3-stage (fp64)
struct SnMeta { const float* w[12]; int O[12]; int M[12]; };
struct SnVMap { short mat[68]; short blk[68]; };

DEV void snv_kernel(SnMeta a, SnVMap mp, double* __restrict__ vbuf, double* __restrict__ vnorm2) {
    int b = blockIdx.x;
    int id = mp.mat[b];
    int m = mp.blk[b] * 256 + threadIdx.x;
    int O = a.O[id], M = a.M[id];
    const float* W = a.w[id];
    __shared__ double red[256];
    double ps = 0.0;
    if (m < M) {
        double s = 0.0;
        for (int o = 0; o < O; ++o) s += (double)W[(size_t)o * M + m];
        s *= 1.0 / sqrt((double)O);
        vbuf[id * 2304 + m] = s;
        ps = s * s;
    }
    red[threadIdx.x] = ps; __syncthreads();
    for (int st = 128; st > 0; st >>= 1) { if (threadIdx.x < st) red[threadIdx.x] += red[threadIdx.x + st]; __syncthreads(); }
    if (threadIdx.x == 0) atomicAdd(vnorm2 + id, red[0]);
}

DEV void snu_kernel(SnMeta a, const double* __restrict__ vbuf,
                    const double* __restrict__ vnorm2, double* __restrict__ unorm2) {
    int wv = blockIdx.x * 4 + (threadIdx.x >> 6);
    int lane = threadIdx.x & 63;
    const int cumR[13] = {0, 256, 512, 768, 1024, 1280, 1536, 1792, 2048, 2304, 2560, 2561, 2661};
    if (wv >= 2661) return;
    int id = 0;
    for (int i = 0; i < 12; ++i) if (wv >= cumR[i]) id = i;
    int o = wv - cumR[id];
    int M = a.M[id];
    const float* Wr = a.w[id] + (size_t)o * M;
    const double* vb = vbuf + id * 2304;
    double s = 0.0;
    for (int m = lane; m < M; m += 64) s += (double)Wr[m] * vb[m];
    for (int off = 32; off > 0; off >>= 1) s += __shfl_down(s, off, 64);
    if (lane == 0) {
        double s1 = 1.0 / (sqrt(vnorm2[id]) + 1e-8);
        double u = s * s1;
        atomicAdd(unorm2 + id, u * u);
    }
}

DEV void snf_kernel(const double* __restrict__ unorm2, float* __restrict__ sig) {
    int t = threadIdx.x;
    if (t < 12) {
        double n2 = unorm2[t];
        sig[t] = (float)(n2 / (sqrt(n2) + 1e-8));
    }
}

// ---------------------------------------------------------------- weight prep: w/sigma -> split bf16 [tap][icc][oc][32ic], hi+lo planes
struct PrepArgs { const float* w[8]; int C[8]; int sigidx[8]; int outoff[8]; int nel[8]; };

DEV void prep_kernel(PrepArgs a, const float* __restrict__ sig, ushort* __restrict__ wp) {
    int gid = blockIdx.x * 256 + threadIdx.x;
    int L = 0, cum = 0;
    for (int i = 0; i < 8; ++i) { if (gid >= cum && gid < cum + a.nel[i]) { L = i; break; } cum += a.nel[i]; }
    if (gid >= cum + a.nel[L]) return;
    int e = gid - cum;
    int C = a.C[L];
    int NICC = (C + 31) >> 5;
    int icl = e & 31;
    int oc = (e >> 5) & 255;
    int icc = (e >> 13) % NICC;
    int tap = e / (8192 * NICC);
    int ic = icc * 32 + icl;
    float v = 0.f;
    if (ic < C) v = a.w[L][((size_t)oc * C + ic) * 9 + tap] / sig[a.sigidx[L]];
    ushort h = f2bf(v);
    ushort l = f2bf(v - bf2f(h));
    wp[a.outoff[L] + e] = h;
    wp[a.outoff[L] + a.nel[L] + e] = l;
}

// ---------------------------------------------------------------- codebook norms (all 4 layers, fp64)
DEV void enprep_kernel(const float* __restrict__ cb0, const float* __restrict__ cb1,
                       const float* __restrict__ cb2, const float* __restrict__ cb3,
                       float* __restrict__ en) {
    int gid = blockIdx.x * 256 + threadIdx.x;    // 0..4095
    int layer = gid >> 10, k = gid & 1023;
    const float* cb = layer == 0 ? cb0 : layer == 1 ? cb1 : layer == 2 ? cb2 : cb3;
    double s = 0.0;
    for (int c = 0; c < 256; ++c) { double v = (double)cb[(size_t)c * 1024 + k]; s += v * v; }
    en[gid] = (float)s;
}

// ---------------------------------------------------------------- codebook split-bf16 prep (one layer -> shared ep buffer)
// ep layout: [icc 8][k 1024][hi32|lo32]
DEV void cbprep_kernel(const float* __restrict__ cb, ushort* __restrict__ ep) {
    int gid = blockIdx.x * 256 + threadIdx.x;    // 0..262143
    int c5 = gid & 31, k = (gid >> 5) & 1023, icc = gid >> 15;
    float v = cb[(size_t)(icc * 32 + c5) * 1024 + k];
    ushort h = f2bf(v);
    ushort l = f2bf(v - bf2f(h));
    size_t o = ((size_t)icc * 1024 + k) * 64 + c5;
    ep[o] = h; ep[o + 32] = l;
}

// ---------------------------------------------------------------- VQ via MFMA: argmin_k (en[k] - 2 x.e_k), then exact direct distance
// Block = 32 pixels x all 1024 codes. 4 waves n-split k (256 each).
DEV void vq2_kernel(const float* __restrict__ h, const float* __restrict__ cb,
                    const ushort* __restrict__ ep, const float* __restrict__ en,
                    float* __restrict__ dacc, int* __restrict__ hist, int HW) {
    __shared__ ushort sA[8 * 32 * 66];             // [icc][p][hi32|lo32], stride 66
    __shared__ unsigned long long sKey[32][65];
    __shared__ int sKst[32];
    __shared__ float sPart[32][8];
    __shared__ double sSum[32];
    int t = threadIdx.x, wid = t >> 6, lane = t & 63, quad = lane >> 4, l15 = lane & 15;
    int pix0 = blockIdx.x * 32, n = pix0 / HW, s0 = pix0 % HW;
    const float* hb = h + (size_t)n * 256 * HW + s0;

    for (int i = t; i < 8192; i += 256) {
        int c = i >> 5, p = i & 31;
        float v = hb[(size_t)c * HW + p];
        ushort hv = f2bf(v), lv = f2bf(v - bf2f(hv));
        int a = (c >> 5) * 2112 + p * 66 + (c & 31);
        sA[a] = hv; sA[a + 32] = lv;
    }
    __syncthreads();

    unsigned long long best[2][4];
    #pragma unroll
    for (int mt = 0; mt < 2; ++mt)
        #pragma unroll
        for (int r = 0; r < 4; ++r) best[mt][r] = ~0ull;

    for (int kp = 0; kp < 2; ++kp) {
        f4v acc[2][8];
        #pragma unroll
        for (int mt = 0; mt < 2; ++mt)
            #pragma unroll
            for (int nt = 0; nt < 8; ++nt) acc[mt][nt] = (f4v){0.f, 0.f, 0.f, 0.f};
        for (int icc = 0; icc < 8; ++icc) {
            #pragma unroll
            for (int ntc = 0; ntc < 2; ++ntc) {
                s8v eh[4], el[4];
                #pragma unroll
                for (int j = 0; j < 4; ++j) {
                    int k = wid * 256 + kp * 128 + (ntc * 4 + j) * 16 + l15;
                    const ushort* q = ep + ((size_t)icc * 1024 + k) * 64 + quad * 8;
                    eh[j] = *(const s8v*)q; el[j] = *(const s8v*)(q + 32);
                }
                #pragma unroll
                for (int mt = 0; mt < 2; ++mt) {
                    int a = icc * 2112 + (mt * 16 + l15) * 66 + quad * 8;
                    s8v ah = *(const s8v*)&sA[a], al = *(const s8v*)&sA[a + 32];
                    #pragma unroll
                    for (int j = 0; j < 4; ++j) {
                        int nt = ntc * 4 + j;
                        acc[mt][nt] = __builtin_amdgcn_mfma_f32_16x16x32_bf16(al, eh[j], acc[mt][nt], 0, 0, 0);
                        acc[mt][nt] = __builtin_amdgcn_mfma_f32_16x16x32_bf16(ah, el[j], acc[mt][nt], 0, 0, 0);
                        acc[mt][nt] = __builtin_amdgcn_mfma_f32_16x16x32_bf16(ah, eh[j], acc[mt][nt], 0, 0, 0);
                    }
                }
            }
        }
        #pragma unroll
        for (int mt = 0; mt < 2; ++mt)
            #pragma unroll
            for (int nt = 0; nt < 8; ++nt) {
                int k = wid * 256 + kp * 128 + nt * 16 + l15;
                float ev = en[k];
                #pragma unroll
                for (int r = 0; r < 4; ++r) {
                    float s = ev - 2.f * acc[mt][nt][r];
                    unsigned ub = __float_as_uint(s);
                    ub = ((int)ub < 0) ? ~ub : (ub | 0x80000000u);   // monotone map (handles negatives)
                    unsigned long long key = ((unsigned long long)ub << 32) | (unsigned)k;
                    if (key < best[mt][r]) best[mt][r] = key;
                }
            }
    }
    #pragma unroll
    for (int mt = 0; mt < 2; ++mt)
        #pragma unroll
        for (int r = 0; r < 4; ++r) {
            int p = mt * 16 + quad * 4 + r;
            sKey[p][wid * 16 + l15] = best[mt][r];
        }
    __syncthreads();
    if (t < 32) {
        unsigned long long m = ~0ull;
        for (int j = 0; j < 64; ++j) { unsigned long long v = sKey[t][j]; if (v < m) m = v; }
        sKst[t] = (int)(unsigned)(m & 0xFFFFFFFFu);
    }
    __syncthreads();
    {   // exact direct-form distance for selected code
        int p = t & 31, sub = t >> 5;
        int ks = sKst[p];
        const float* ec = cb + ks;
        float d = 0.f;
        for (int c = sub * 32; c < sub * 32 + 32; ++c) {
            float xv = hb[(size_t)c * HW + p];
            float evv = ec[(size_t)c * 1024];
            float df = xv - evv;
            d += df * df;
        }
        sPart[p][sub] = d;
    }
    __syncthreads();
    if (t < 32) {
        float s = 0.f;
        for (int j = 0; j < 8; ++j) s += sPart[t][j];
        sSum[t] = (double)s;
        if (hist) atomicAdd(hist + sKst[t], 1);
    }
    __syncthreads();
    if (t == 0) {
        double s = 0.0;
        for (int i = 0; i < 32; ++i) s += sSum[i];
        atomicAdd(dacc + n, (float)s);
    }
}

// ---------------------------------------------------------------- MFMA implicit-GEMM 3x3 conv, pad 1
template<int ST, int NW, int NTW, int NICC, bool RELU, bool POOL, bool RES, bool INS, bool OUTS>
__global__ __launch_bounds__(NW * 64) void conv_mfma(
        const float* __restrict__ in, const ushort* __restrict__ ins,
        const ushort* __restrict__ wp, const float* __restrict__ bias,
        const float* __restrict__ res, float* __restrict__ out,
        ushort* __restrict__ outs, int C, int H) {
    const int MT = ST * 4;
    const int PLANE = NICC * 73728;           // 9*NICC*256*32
    __shared__ ushort sA[ST * 100 * 72];
    int t = threadIdx.x;
    int wid = t >> 6, lane = t & 63, quad = lane >> 4, l15 = lane & 15;
    int n = blockIdx.z;
    int ocb = blockIdx.y * (NW * NTW * 16) + wid * (NTW * 16);
    int tpr = H >> 3;
    int tIdx0 = blockIdx.x * ST;

    int abase[MT];
    #pragma unroll
    for (int mt = 0; mt < MT; ++mt) {
        int m64 = (mt & 3) * 16 + l15;
        abase[mt] = (((mt >> 2) * 100 + (m64 >> 3) * 10 + (m64 & 7)) * 72) + quad * 8;
    }

    f4v acc[MT][NTW];
    #pragma unroll
    for (int mt = 0; mt < MT; ++mt)
        #pragma unroll
        for (int nt = 0; nt < NTW; ++nt)
            acc[mt][nt] = (f4v){0.f, 0.f, 0.f, 0.f};

    for (int icc = 0; icc < NICC; ++icc) {
        __syncthreads();
        if (INS) {
            for (int i = t; i < ST * 100 * 8; i += NW * 64) {
                int pg = i >> 3, part = i & 7;
                int tile = pg / 100, pos = pg - tile * 100;
                int tIdx = tIdx0 + tile;
                int th0 = (tIdx / tpr) * 8, tw0 = (tIdx % tpr) * 8;
                int gy = th0 - 1 + pos / 10, gx = tw0 - 1 + (pos % 10);
                s8v v = (s8v){0, 0, 0, 0, 0, 0, 0, 0};
                if (gy >= 0 && gy < H && gx >= 0 && gx < H)
                    v = *(const s8v*)(ins + ((((size_t)n * H + gy) * H + gx) * 8 + icc) * 64 + part * 8);
                *(s8v*)(&sA[(tile * 100 + pos) * 72 + part * 8]) = v;
            }
        } else {
            for (int i = t; i < ST * 100 * 32; i += NW * 64) {
                int ic = i / (ST * 100);
                int rr = i - ic * (ST * 100);
                int tile = rr / 100, pos = rr - (rr / 100) * 100;
                int tIdx = tIdx0 + tile;
                int th0 = (tIdx / tpr) * 8, tw0 = (tIdx % tpr) * 8;
                int gy = th0 - 1 + pos / 10, gx = tw0 - 1 + (pos % 10);
                int gic = icc * 32 + ic;
                ushort hv = 0, lv = 0;
                if (gic < C && gy >= 0 && gy < H && gx >= 0 && gx < H) {
                    float v = in[(((size_t)n * C + gic) * H + gy) * H + gx];
                    if (RELU) v = fmaxf(v, 0.f);
                    hv = f2bf(v);
                    lv = f2bf(v - bf2f(hv));
                }
                int si = (tile * 100 + pos) * 72 + ic;
                sA[si] = hv; sA[si + 32] = lv;
            }
        }
        __syncthreads();

        s8v bh[2][NTW], bl[2][NTW];
        {
            size_t wb = (size_t)(0 * NICC + icc) * 8192;
            #pragma unroll
            for (int nt = 0; nt < NTW; ++nt) {
                size_t wo = wb + (size_t)(ocb + nt * 16 + l15) * 32 + quad * 8;
                bh[0][nt] = *(const s8v*)(wp + wo);
                bl[0][nt] = *(const s8v*)(wp + PLANE + wo);
            }
        }
        #pragma unroll
        for (int tap = 0; tap < 9; ++tap) {
            int cb = tap & 1;
            if (tap < 8) {
                size_t wb = (size_t)((tap + 1) * NICC + icc) * 8192;
                #pragma unroll
                for (int nt = 0; nt < NTW; ++nt) {
                    size_t wo = wb + (size_t)(ocb + nt * 16 + l15) * 32 + quad * 8;
                    bh[(tap + 1) & 1][nt] = *(const s8v*)(wp + wo);
                    bl[(tap + 1) & 1][nt] = *(const s8v*)(wp + PLANE + wo);
                }
            }
            int toff = ((tap / 3) * 10 + (tap % 3)) * 72;
            #pragma unroll
            for (int mt = 0; mt < MT; ++mt) {
                s8v ah = *(const s8v*)(&sA[abase[mt] + toff]);
                s8v al = *(const s8v*)(&sA[abase[mt] + toff + 32]);
                #pragma unroll
                for (int nt = 0; nt < NTW; ++nt) {
                    acc[mt][nt] = __builtin_amdgcn_mfma_f32_16x16x32_bf16(al, bh[cb][nt], acc[mt][nt], 0, 0, 0);
                    acc[mt][nt] = __builtin_amdgcn_mfma_f32_16x16x32_bf16(ah, bl[cb][nt], acc[mt][nt], 0, 0, 0);
                    acc[mt][nt] = __builtin_amdgcn_mfma_f32_16x16x32_bf16(ah, bh[cb][nt], acc[mt][nt], 0, 0, 0);
                }
            }
        }
    }

    #pragma unroll
    for (int nt = 0; nt < NTW; ++nt) {
        int oc = ocb + nt * 16 + l15;
        float bv = bias[oc];
        #pragma unroll
        for (int mt = 0; mt < MT; ++mt) {
            int tIdx = tIdx0 + (mt >> 2);
            int th0 = (tIdx / tpr) * 8, tw0 = (tIdx % tpr) * 8;
            if (POOL) {
                float s01 = acc[mt][nt][0] + acc[mt][nt][1];
                float s23 = acc[mt][nt][2] + acc[mt][nt][3];
                float o01 = s01 + __shfl_down(s01, 32, 64);
                float o23 = s23 + __shfl_down(s23, 32, 64);
                if (quad < 2) {
                    int Ho = H >> 1;
                    int oy = (th0 >> 1) + (mt & 3);
                    int ox = (tw0 >> 1) + quad * 2;
                    size_t ob = ((size_t)(n * 256 + oc) * Ho + oy) * Ho;
                    out[ob + ox] = 0.25f * o01 + bv;
                    out[ob + ox + 1] = 0.25f * o23 + bv;
                }
            } else if (OUTS) {
                int iccg = oc >> 5, ocw = oc & 31;
                #pragma unroll
                for (int r = 0; r < 4; ++r) {
                    int p16 = quad * 4 + r;
                    int y = th0 + (mt & 3) * 2 + (p16 >> 3);
                    int x = tw0 + (p16 & 7);
                    float v = fmaxf(acc[mt][nt][r] + bv, 0.f);
                    ushort h = f2bf(v);
                    size_t ob = ((((size_t)n * H + y) * H + x) * 8 + iccg) * 64;
                    outs[ob + ocw] = h;
                    outs[ob + 32 + ocw] = f2bf(v - bf2f(h));
                }
            } else {
                #pragma unroll
                for (int r = 0; r < 4; ++r) {
                    int p16 = quad * 4 + r;
                    int y = th0 + (mt & 3) * 2 + (p16 >> 3);
                    int x = tw0 + (p16 & 7);
                    size_t oi = (((size_t)(n * 256 + oc)) * H + y) * H + x;
                    float v = acc[mt][nt][r] + bv;
                    if (RES) v += res[oi];
                    out[oi] = v;
                }
            }
        }
    }
}

// ---------------------------------------------------------------- block-0 shortcut: h1 += conv1x1(pool2(x)) + b
DEV void sc0_kernel(const float* __restrict__ x, const float* __restrict__ wsc,
                    const float* __restrict__ bsc, const float* __restrict__ sig,
                    float* __restrict__ h1) {
    int idx = blockIdx.x * 256 + threadIdx.x;
    int ow = idx & 15, oh = (idx >> 4) & 15, oc = (idx >> 8) & 255, n = idx >> 16;
    float scale = 1.f / sig[0];
    float acc = bsc[oc];
    #pragma unroll
    for (int ic = 0; ic < 3; ++ic) {
        const float* xb = x + (((size_t)(n * 3 + ic)) * 32 + oh * 2) * 32 + ow * 2;
        float pv = 0.25f * (xb[0] + xb[1] + xb[32] + xb[33]);
        acc += pv * (wsc[oc * 3 + ic] * scale);
    }
    h1[idx] += acc;
}

// ---------------------------------------------------------------- block-1 shortcut: h2 += conv1x1(pool2(h1)) + b
DEV void sc1_kernel(const float* __restrict__ h1, const float* __restrict__ wsc,
                    const float* __restrict__ bsc, const float* __restrict__ sig,
                    float* __restrict__ h2) {
    __shared__ float sP[64][64];
    __shared__ float sWs[64][65];
    int t = threadIdx.x;
    int n = blockIdx.x, ocb = blockIdx.y * 64;
    int ocg = t & 15, pgr = t >> 4;
    float scale = 1.f / sig[0];
    float acc[4][4] = {};
    for (int c0 = 0; c0 < 256; c0 += 64) {
        __syncthreads();
        for (int i = t; i < 4096; i += 256) {
            int ic = i >> 6, p = i & 63;
            int oh = p >> 3, ow = p & 7;
            const float* hb = h1 + (((size_t)(n * 256 + c0 + ic)) * 16 + oh * 2) * 16 + ow * 2;
            sP[ic][p] = 0.25f * (hb[0] + hb[1] + hb[16] + hb[17]);
            int oc = i >> 6, ic2 = i & 63;
            sWs[oc][ic2] = wsc[(size_t)(ocb + oc) * 256 + c0 + ic2] * scale;
        }
        __syncthreads();
        for (int ic = 0; ic < 64; ++ic) {
            float pv[4];
            #pragma unroll
            for (int q = 0; q < 4; ++q) pv[q] = sP[ic][pgr * 4 + q];
            #pragma unroll
            for (int j = 0; j < 4; ++j) {
                float wv = sWs[ocg + 16 * j][ic];
                #pragma unroll
                for (int q = 0; q < 4; ++q) acc[j][q] += wv * pv[q];
            }
        }
    }
    #pragma unroll
    for (int j = 0; j < 4; ++j) {
        int oc = ocb + ocg + 16 * j;
        float bv = bsc[oc];
        #pragma unroll
        for (int q = 0; q < 4; ++q) {
            size_t oi = ((size_t)(n * 256 + oc)) * 64 + pgr * 4 + q;
            h2[oi] += acc[j][q] + bv;
        }
    }
}

// ---------------------------------------------------------------- head + ppl
DEV void head_kernel(const float* __restrict__ h4, const float* __restrict__ lin_w,
                     const float* __restrict__ lin_b, const float* __restrict__ emb_w,
                     const int* __restrict__ y, const float* __restrict__ sig,
                     const float* __restrict__ dacc, float* __restrict__ out) {
    __shared__ double r1[256], r2[256];
    int b = blockIdx.x, t = threadIdx.x;
    const float* hb = h4 + ((size_t)b * 256 + t) * 64;
    float s = 0.f;
    #pragma unroll 4
    for (int i = 0; i < 64; ++i) s += fmaxf(hb[i], 0.f);
    int yb = y[b];
    r1[t] = (double)s * (double)lin_w[t];
    r2[t] = (double)s * (double)emb_w[(size_t)yb * 256 + t];
    __syncthreads();
    for (int st = 128; st > 0; st >>= 1) { if (t < st) { r1[t] += r1[t + st]; r2[t] += r2[t + st]; } __syncthreads(); }
    if (t == 0) {
        out[b] = (float)(r1[0] / (double)sig[10] + (double)lin_b[0] + r2[0] / (double)sig[11]);
        out[64 + b] = (float)(0.5 * ((double)dacc[b] * (1.0 / 65536.0)
                              + ((double)dacc[64 + b] + (double)dacc[128 + b] + (double)dacc[192 + b]) * (1.0 / 16384.0)));
    }
}

DEV void ppl_kernel(const int* __restrict__ hist, float* __restrict__ outp) {
    __shared__ double red[256];
    int t = threadIdx.x;
    double s = 0.0;
    for (int k = t; k < 1024; k += 256) {
        double p = (double)hist[k] * (1.0 / 4096.0);
        s += p * log(p + 1e-10);
    }
    red[t] = s; __syncthreads();
    for (int st = 128; st > 0; st >>= 1) { if (t < st) red[t] += red[t + st]; __syncthreads(); }
    if (t == 0) outp[0] = (float)exp(-red[0]);
}

// ---------------------------------------------------------------- launch
extern "C" void kernel_launch(void* const* d_in, const int* in_sizes, int n_in,
                              void* d_out, int out_size, void* d_ws, size_t ws_size,
                              hipStream_t stream) {
    (void)in_sizes; (void)n_in; (void)out_size; (void)ws_size;
    const float* x      = (const float*)d_in[0];
    const int*   y      = (const int*)  d_in[1];
    const float* b0_w1  = (const float*)d_in[2];
    const float* b0_b1  = (const float*)d_in[3];
    const float* b0_w2  = (const float*)d_in[4];
    const float* b0_b2  = (const float*)d_in[5];
    const float* b0_wsc = (const float*)d_in[6];
    const float* b0_bsc = (const float*)d_in[7];
    const float* b1_w1  = (const float*)d_in[8];
    const float* b1_b1  = (const float*)d_in[9];
    const float* b1_w2  = (const float*)d_in[10];
    const float* b1_b2  = (const float*)d_in[11];
    const float* b1_wsc = (const float*)d_in[12];
    const float* b1_bsc = (const float*)d_in[13];
    const float* b2_w1  = (const float*)d_in[14];
    const float* b2_b1  = (const float*)d_in[15];
    const float* b2_w2  = (const float*)d_in[16];
    const float* b2_b2  = (const float*)d_in[17];
    const float* b3_w1  = (const float*)d_in[18];
    const float* b3_b1  = (const float*)d_in[19];
    const float* b3_w2  = (const float*)d_in[20];
    const float* b3_b2  = (const float*)d_in[21];
    const float* cb0    = (const float*)d_in[22];
    const float* cb1    = (const float*)d_in[23];
    const float* cb2    = (const float*)d_in[24];
    const float* cb3    = (const float*)d_in[25];
    const float* lin_w  = (const float*)d_in[26];
    const float* lin_b  = (const float*)d_in[27];
    const float* emb_w  = (const float*)d_in[28];
    float* out = (float*)d_out;

    // ---- workspace map (float indices) ----
    float* wsf  = (float*)d_ws;
    float* sig  = wsf;                                           // [0,16)
    float* dacc = wsf + 16;                                      // [16,272)
    double* vnorm2 = (double*)(wsf + 512);                       // [512,536)
    double* unorm2 = (double*)(wsf + 544);                       // [544,568)
    int*   hist = (int*)(wsf + 1296);                            // [1296,2320) ints
    float* en   = wsf + 4096;                                    // [4096,8192)
    ushort* Aus  = (ushort*)(wsf + 65536);                       // [65536,16842752) f (conv0_1 out, NHWC-split)
    ushort* tbus = (ushort*)(wsf + 65536);                       // aliases dead A
    ushort* t2us = (ushort*)(wsf + 4259840);                     // aliases dead A
    float* h1 = wsf + 16842752;                                  // [16842752,21037056)
    float* h2 = h1 + 4194304;                                    // [21037056,22085632)
    float* h3 = h2 + 1048576;                                    // [22085632,23134208)
    float* h4 = h3 + 1048576;                                    // [23134208,24182784)
    ushort* wp = (ushort*)(wsf + 24182784);                      // ends f 28385280
    double* vbuf = (double*)(wsf + 28385280);                    // ends f 28440576
    ushort* ep = (ushort*)(wsf + 28440576);                      // 262144 f -> ends f 28702720 (114.8 MB)

    hipMemsetAsync(dacc, 0, 256 * sizeof(float), stream);
    hipMemsetAsync(wsf + 512, 0, 256, stream);                   // vnorm2 + unorm2
    hipMemsetAsync(hist, 0, 1024 * sizeof(int), stream);

    SnMeta sm;
    const float* sw[12] = {b0_w1, b0_w2, b0_wsc, b1_w1, b1_w2, b1_wsc,
                           b2_w1, b2_w2, b3_w1, b3_w2, lin_w, emb_w};
    int sO[12] = {256, 256, 256, 256, 256, 256, 256, 256, 256, 256, 1, 100};
    int sM[12] = {27, 2304, 3, 2304, 2304, 256, 2304, 2304, 2304, 2304, 256, 256};
    for (int i = 0; i < 12; ++i) { sm.w[i] = sw[i]; sm.O[i] = sO[i]; sm.M[i] = sM[i]; }
    SnVMap mp;
    {
        int bi = 0;
        for (int i = 0; i < 12; ++i) {
            int nb = (sM[i] + 255) / 256;
            for (int j = 0; j < nb; ++j) { mp.mat[bi] = (short)i; mp.blk[bi] = (short)j; ++bi; }
        }
    }
    snv_kernel<<<68, 256, 0, stream>>>(sm, mp, vbuf, vnorm2);
    snu_kernel<<<666, 256, 0, stream>>>(sm, vbuf, vnorm2, unorm2);
    snf_kernel<<<1, 64, 0, stream>>>(unorm2, sig);

    PrepArgs pa;
    const float* pw[8] = {b0_w1, b0_w2, b1_w1, b1_w2, b2_w1, b2_w2, b3_w1, b3_w2};
    int pC[8]   = {3, 256, 256, 256, 256, 256, 256, 256};
    int pS[8]   = {0, 1, 3, 4, 6, 7, 8, 9};
    int pOff[8] = {0, 147456, 1327104, 2506752, 3686400, 4866048, 6045696, 7225344};
    int pN[8]   = {73728, 589824, 589824, 589824, 589824, 589824, 589824, 589824};
    for (int i = 0; i < 8; ++i) { pa.w[i] = pw[i]; pa.C[i] = pC[i]; pa.sigidx[i] = pS[i]; pa.outoff[i] = pOff[i]; pa.nel[i] = pN[i]; }
    prep_kernel<<<16416, 256, 0, stream>>>(pa, sig, wp);
    enprep_kernel<<<16, 256, 0, stream>>>(cb0, cb1, cb2, cb3, en);

    // block 0
    conv_mfma<2, 4, 2, 1, false, false, false, false, true><<<dim3(8, 2, 64), 256, 0, stream>>>(
        x, nullptr, wp + 0, b0_b1, nullptr, nullptr, Aus, 3, 32);
    conv_mfma<2, 4, 2, 8, false, true, false, true, false><<<dim3(8, 2, 64), 256, 0, stream>>>(
        nullptr, Aus, wp + 147456, b0_b2, nullptr, h1, nullptr, 256, 32);
    sc0_kernel<<<16384, 256, 0, stream>>>(x, b0_wsc, b0_bsc, sig + 2, h1);
    cbprep_kernel<<<1024, 256, 0, stream>>>(cb0, ep);
    vq2_kernel<<<512, 256, 0, stream>>>(h1, cb0, ep, en + 0, dacc + 0, nullptr, 256);

    // block 1
    conv_mfma<2, 4, 1, 8, true, false, false, false, true><<<dim3(2, 4, 64), 256, 0, stream>>>(
        h1, nullptr, wp + 1327104, b1_b1, nullptr, nullptr, tbus, 256, 16);
    conv_mfma<2, 4, 1, 8, false, true, false, true, false><<<dim3(2, 4, 64), 256, 0, stream>>>(
        nullptr, tbus, wp + 2506752, b1_b2, nullptr, h2, nullptr, 256, 16);
    sc1_kernel<<<dim3(64, 4), 256, 0, stream>>>(h1, b1_wsc, b1_bsc, sig + 5, h2);
    cbprep_kernel<<<1024, 256, 0, stream>>>(cb1, ep);
    vq2_kernel<<<128, 256, 0, stream>>>(h2, cb1, ep, en + 1024, dacc + 64, nullptr, 64);

    // block 2
    conv_mfma<1, 2, 1, 8, true, false, false, false, true><<<dim3(1, 8, 64), 128, 0, stream>>>(
        h2, nullptr, wp + 3686400, b2_b1, nullptr, nullptr, t2us, 256, 8);
    conv_mfma<1, 2, 1, 8, false, false, true, true, false><<<dim3(1, 8, 64), 128, 0, stream>>>(
        nullptr, t2us, wp + 4866048, b2_b2, h2, h3, nullptr, 256, 8);
    cbprep_kernel<<<1024, 256, 0, stream>>>(cb2, ep);
    vq2_kernel<<<128, 256, 0, stream>>>(h3, cb2, ep, en + 2048, dacc + 128, nullptr, 64);

    // block 3
    conv_mfma<1, 2, 1, 8, true, false, false, false, true><<<dim3(1, 8, 64), 128, 0, stream>>>(
        h3, nullptr, wp + 6045696, b3_b1, nullptr, nullptr, t2us, 256, 8);
    conv_mfma<1, 2, 1, 8, false, false, true, true, false><<<dim3(1, 8, 64), 128, 0, stream>>>(
        nullptr, t2us, wp + 7225344, b3_b2, h3, h4, nullptr, 256, 8);
    cbprep_kernel<<<1024, 256, 0, stream>>>(cb3, ep);
    vq2_kernel<<<128, 256, 0, stream>>>(h4, cb3, ep, en + 3072, dacc + 192, hist, 64);

    head_kernel<<<64, 256, 0, stream>>>(h4, lin_w, lin_b, emb_w, y, sig, dacc, out);
    ppl_kernel<<<1, 256, 0, stream>>>(hist, out + 128);
}